// Round 10
// baseline (2404.263 us; speedup 1.0000x reference)
//
#include <hip/hip_runtime.h>
#include <hip/hip_bf16.h>

// Problem constants (from reference)
#define NUM_USERS 100000
#define NUM_ITEMS 50000
#define N_NODES   150000   // NUM_USERS + NUM_ITEMS
#define EMB       64
#define NNZ       2400000
#define BATCH     16384
#define D_CAT     384      // EMB*3*2
#define BSHIFT    8        // 256 rows per bucket (round-9 lesson: segment >= line)
#define NBUCK     ((N_NODES + 255) >> 8)   // 586
#define EPB       8192     // edges per multisplit block

// ---- bf16 helpers (bit-level, RN-even for f32->bf16) -----------------------
__device__ __forceinline__ unsigned short f2bf(float f) {
    unsigned u = __float_as_uint(f);
    unsigned r = u + 0x7fffu + ((u >> 16) & 1u);
    return (unsigned short)(r >> 16);
}
__device__ __forceinline__ float bflo(unsigned u) { return __uint_as_float(u << 16); }
__device__ __forceinline__ float bfhi(unsigned u) { return __uint_as_float(u & 0xffff0000u); }

// ---------------------------------------------------------------------------
// Bucket histogram, LDS-aggregated (one global atomic per non-empty bucket
// per block; round-8 lesson: device atomics are memory-side ~32 B each).
// ---------------------------------------------------------------------------
__global__ __launch_bounds__(1024) void bucket_hist(const int* __restrict__ rows,
                                                    int* __restrict__ bcnt, int nnz) {
    __shared__ int h[NBUCK];
    int tid = threadIdx.x;
    for (int i = tid; i < NBUCK; i += 1024) h[i] = 0;
    __syncthreads();
    for (int i = blockIdx.x * 1024 + tid; i < nnz; i += gridDim.x * 1024)
        atomicAdd(&h[rows[i] >> BSHIFT], 1);
    __syncthreads();
    for (int i = tid; i < NBUCK; i += 1024) {
        int c = h[i];
        if (c) atomicAdd(&bcnt[i], c);
    }
}

// ---------------------------------------------------------------------------
// Exclusive scan over the 586 bucket counts (single block, 1 elem/thread).
// Emits boffs (+sentinel) and gtails (mutable copy for the multisplit).
// ---------------------------------------------------------------------------
__global__ __launch_bounds__(1024) void bucket_scan(const int* __restrict__ bcnt,
                                                    int* __restrict__ boffs,
                                                    int* __restrict__ gtails, int nnz) {
    __shared__ int s[1024];
    int t = threadIdx.x;
    int x = (t < NBUCK) ? bcnt[t] : 0;
    s[t] = x;
    __syncthreads();
#pragma unroll
    for (int off = 1; off < 1024; off <<= 1) {
        int v = (t >= off) ? s[t - off] : 0;
        __syncthreads();
        s[t] += v;
        __syncthreads();
    }
    if (t < NBUCK) {
        int e = s[t] - x;
        boffs[t] = e;
        gtails[t] = e;
    }
    if (t == 0) boffs[NBUCK] = nnz;
}

// ---------------------------------------------------------------------------
// LDS-staged multisplit into 256-row buckets. Per-block per-bucket segment is
// now ~14 edges (~2 lines) -> near-single-CU line ownership.
// pv payload: .x = (r_local<<18) | col  (rl<256, col<2^18), .y = val
// ---------------------------------------------------------------------------
__global__ __launch_bounds__(1024) void coarse_multisplit(const int* __restrict__ rows,
                                                          const int* __restrict__ cols,
                                                          const float* __restrict__ vals,
                                                          int* __restrict__ gtails,
                                                          int2* __restrict__ pv, int nnz) {
    __shared__ int hcnt[NBUCK];
    int tid = threadIdx.x;
    int e0 = blockIdx.x * EPB;
    int e1 = e0 + EPB < nnz ? e0 + EPB : nnz;

    for (int i = tid; i < NBUCK; i += 1024) hcnt[i] = 0;
    __syncthreads();
    for (int i = e0 + tid; i < e1; i += 1024)
        atomicAdd(&hcnt[rows[i] >> BSHIFT], 1);
    __syncthreads();
    for (int i = tid; i < NBUCK; i += 1024) {
        int c = hcnt[i];
        if (c) hcnt[i] = atomicAdd(&gtails[i], c);   // global base for this block
    }
    __syncthreads();
    for (int i = e0 + tid; i < e1; i += 1024) {
        int r = rows[i];
        int pos = atomicAdd(&hcnt[r >> BSHIFT], 1);  // LDS bump from global base
        pv[pos] = make_int2(((r & 255) << 18) | cols[i], __float_as_int(vals[i]));
    }
}

// ---------------------------------------------------------------------------
// Fused SPMM: out[r] = relu( Z[r] + sum_edges v*Z[c] + bias ), per bucket.
// One block per 256-row bucket; fp32 row accumulators in LDS (64 KB,
// accX/accY planes so lane k -> bank k, 2-way aliasing = free). Edges are
// consumed UNORDERED from the bucket's contiguous pv segment — this deletes
// the fine_scatter row-sort kernel and row_ptr entirely. 4-deep gather
// pipeline per half-wave; LDS atomicAdd (ds_add_f32) resolves row collisions.
// ---------------------------------------------------------------------------
__global__ __launch_bounds__(512) void bucket_spmm(const int* __restrict__ boffs,
                                                   const int2* __restrict__ pv,
                                                   const unsigned* __restrict__ zh,   // bf16x2, 32/row
                                                   const float* __restrict__ bias,    // [64] fp32
                                                   unsigned* __restrict__ outh) {     // bf16x2, 32/row
    __shared__ float accX[256 * 32];   // col 2k
    __shared__ float accY[256 * 32];   // col 2k+1
    int b = blockIdx.x;
    int tid = threadIdx.x;
    int r0 = b << BSHIFT;
    int nr = N_NODES - r0; if (nr > 256) nr = 256;
    int k = tid & 31;
    int hw = tid >> 5;                 // 0..15 half-waves

    // init accumulators with the self-loop term Z[r]
    for (int i = tid; i < nr * 32; i += 512) {
        unsigned u = zh[(size_t)(r0 + (i >> 5)) * 32 + (i & 31)];
        accX[i] = bflo(u);
        accY[i] = bfhi(u);
    }
    __syncthreads();

    int lo = boffs[b], hi = boffs[b + 1];
    int nfull = (hi - lo) & ~63;       // 64 edges per round (16 hw x 4)
    for (int i = lo + hw * 4; i < lo + nfull; i += 64) {
        int2 p0 = pv[i + 0];
        int2 p1 = pv[i + 1];
        int2 p2 = pv[i + 2];
        int2 p3 = pv[i + 3];
        unsigned z0 = zh[(size_t)(p0.x & 0x3FFFF) * 32 + k];
        unsigned z1 = zh[(size_t)(p1.x & 0x3FFFF) * 32 + k];
        unsigned z2 = zh[(size_t)(p2.x & 0x3FFFF) * 32 + k];
        unsigned z3 = zh[(size_t)(p3.x & 0x3FFFF) * 32 + k];
        float v0 = __int_as_float(p0.y), v1 = __int_as_float(p1.y);
        float v2 = __int_as_float(p2.y), v3 = __int_as_float(p3.y);
        int a0 = (p0.x >> 18) * 32 + k;
        int a1 = (p1.x >> 18) * 32 + k;
        int a2 = (p2.x >> 18) * 32 + k;
        int a3 = (p3.x >> 18) * 32 + k;
        atomicAdd(&accX[a0], v0 * bflo(z0)); atomicAdd(&accY[a0], v0 * bfhi(z0));
        atomicAdd(&accX[a1], v1 * bflo(z1)); atomicAdd(&accY[a1], v1 * bfhi(z1));
        atomicAdd(&accX[a2], v2 * bflo(z2)); atomicAdd(&accY[a2], v2 * bfhi(z2));
        atomicAdd(&accX[a3], v3 * bflo(z3)); atomicAdd(&accY[a3], v3 * bfhi(z3));
    }
    for (int i = lo + nfull + hw; i < hi; i += 16) {
        int2 p = pv[i];
        unsigned z = zh[(size_t)(p.x & 0x3FFFF) * 32 + k];
        float v = __int_as_float(p.y);
        int a = (p.x >> 18) * 32 + k;
        atomicAdd(&accX[a], v * bflo(z));
        atomicAdd(&accY[a], v * bfhi(z));
    }
    __syncthreads();

    // epilogue: bias + relu + bf16 pack, coalesced
    for (int i = tid; i < nr * 32; i += 512) {
        int kk = i & 31;
        float2 bv = *(const float2*)(bias + 2 * kk);
        float x = fmaxf(accX[i] + bv.x, 0.f);
        float y = fmaxf(accY[i] + bv.y, 0.f);
        outh[(size_t)(r0 + (i >> 5)) * 32 + kk] =
            ((unsigned)f2bf(y) << 16) | (unsigned)f2bf(x);
    }
}

// ---------------------------------------------------------------------------
// Convert concat(uEmb,iEmb) fp32 -> bf16 table (4 elems / thread)
// ---------------------------------------------------------------------------
__global__ __launch_bounds__(256) void cvt_feat0(const float4* __restrict__ a, int na4,
                                                 const float4* __restrict__ b, int nb4,
                                                 ushort4* __restrict__ dst) {
    int i = blockIdx.x * 256 + threadIdx.x;
    if (i >= na4 + nb4) return;
    float4 v = (i < na4) ? a[i] : b[i - na4];
    ushort4 o;
    o.x = f2bf(v.x); o.y = f2bf(v.y); o.z = f2bf(v.z); o.w = f2bf(v.w);
    dst[i] = o;
}

// ---------------------------------------------------------------------------
// Z = X @ W   (X: bf16 table [n x 64], W: fp32 [64 x 64], Z: bf16 [n x 64])
// ((L+I)X)W == (L+I)(XW): GEMM before spmm; all inner-loop reads are LDS.
// ---------------------------------------------------------------------------
__global__ __launch_bounds__(256) void gemm_table_bf16(const unsigned* __restrict__ Xh,
                                                       const float* __restrict__ W,
                                                       unsigned short* __restrict__ Zh,
                                                       int n_rows) {
    __shared__ float Wl[64 * 64];        // 16 KB
    __shared__ uint4 Xl4[64 * 8];        // 8 KB: 64 rows x 32 uints (bf16x2)
    int tid = threadIdx.x;
    int lane = tid & 63;
    int wave = tid >> 6;
    int r0 = blockIdx.x * 64;
    int nr = n_rows - r0; if (nr > 64) nr = 64;

    for (int i = tid; i < 64 * 64; i += 256) Wl[i] = W[i];
    const uint4* Xg4 = (const uint4*)(Xh + (size_t)r0 * 32);
    for (int i = tid; i < nr * 8; i += 256) Xl4[i] = Xg4[i];
    __syncthreads();

    const unsigned* Xl = (const unsigned*)Xl4;
    int rbase = wave * 16;
    float acc[16];
#pragma unroll
    for (int i = 0; i < 16; ++i) acc[i] = 0.f;

#pragma unroll 1
    for (int kc = 0; kc < 8; ++kc) {     // 8 k-values per chunk
        float w0 = Wl[(kc * 8 + 0) * 64 + lane];
        float w1 = Wl[(kc * 8 + 1) * 64 + lane];
        float w2 = Wl[(kc * 8 + 2) * 64 + lane];
        float w3 = Wl[(kc * 8 + 3) * 64 + lane];
        float w4 = Wl[(kc * 8 + 4) * 64 + lane];
        float w5 = Wl[(kc * 8 + 5) * 64 + lane];
        float w6 = Wl[(kc * 8 + 6) * 64 + lane];
        float w7 = Wl[(kc * 8 + 7) * 64 + lane];
#pragma unroll
        for (int i = 0; i < 16; ++i) {
            uint4 q = *(const uint4*)&Xl[(rbase + i) * 32 + kc * 4];  // broadcast
            acc[i] = fmaf(bflo(q.x), w0, acc[i]);
            acc[i] = fmaf(bfhi(q.x), w1, acc[i]);
            acc[i] = fmaf(bflo(q.y), w2, acc[i]);
            acc[i] = fmaf(bfhi(q.y), w3, acc[i]);
            acc[i] = fmaf(bflo(q.z), w4, acc[i]);
            acc[i] = fmaf(bfhi(q.z), w5, acc[i]);
            acc[i] = fmaf(bflo(q.w), w6, acc[i]);
            acc[i] = fmaf(bfhi(q.w), w7, acc[i]);
        }
    }
#pragma unroll
    for (int i = 0; i < 16; ++i) {
        int r = r0 + rbase + i;
        if (r < n_rows) Zh[(size_t)r * 64 + lane] = f2bf(acc[i]);
    }
}

// ---------------------------------------------------------------------------
// Gather concatenated per-sample features -> bf16 E (one 384-thread block/row)
// ---------------------------------------------------------------------------
__global__ __launch_bounds__(384) void gather_e(const int* __restrict__ userIdx,
                                                const int* __restrict__ itemIdx,
                                                const float* __restrict__ uEmb,
                                                const float* __restrict__ iEmb,
                                                const unsigned short* __restrict__ feat1h,
                                                const unsigned short* __restrict__ feat2h,
                                                unsigned short* __restrict__ E) {
    int b = blockIdx.x;
    int j = threadIdx.x;          // 0..383
    int half = j >= 192;
    int jj = half ? (j - 192) : j;
    int seg = jj >> 6;
    int k = jj & 63;
    unsigned short v;
    if (half == 0) {
        int u = userIdx[b];
        if (seg == 0)      v = f2bf(uEmb[(size_t)u * 64 + k]);
        else if (seg == 1) v = feat1h[(size_t)u * 64 + k];
        else               v = feat2h[(size_t)u * 64 + k];
    } else {
        int it = itemIdx[b];
        if (seg == 0)      v = f2bf(iEmb[(size_t)it * 64 + k]);
        else if (seg == 1) v = feat1h[(size_t)(it + NUM_USERS) * 64 + k];
        else               v = feat2h[(size_t)(it + NUM_USERS) * 64 + k];
    }
    E[(size_t)b * D_CAT + j] = v;
}

// ---------------------------------------------------------------------------
// H1[r][c] = relu( b1[c] + sum_{k<384} E[r][k] * W1[k][c] ), E bf16.
// ---------------------------------------------------------------------------
__global__ __launch_bounds__(256) void gemm384_bf16_relu(const unsigned short* __restrict__ E,
                                                         const float* __restrict__ W,
                                                         const float* __restrict__ bia,
                                                         float* __restrict__ H1,
                                                         int n_rows) {
    __shared__ float Wl[128 * 64];   // 32 KB
    int tid = threadIdx.x;
    int lane = tid & 63;
    int wave = tid >> 6;
    int r0 = blockIdx.x * 64 + wave * 16;
    int last = n_rows - 1;

    const unsigned short* rowp[16];
#pragma unroll
    for (int i = 0; i < 16; ++i) {
        int r = r0 + i;
        r = r > last ? last : r;
        rowp[i] = E + (size_t)r * D_CAT;
    }
    float acc[16];
    float bv = bia[lane];
#pragma unroll
    for (int i = 0; i < 16; ++i) acc[i] = bv;

    for (int k0 = 0; k0 < D_CAT; k0 += 128) {
        if (k0) __syncthreads();
        for (int i = tid; i < 128 * 64; i += 256) Wl[i] = W[k0 * 64 + i];
        __syncthreads();
#pragma unroll 1
        for (int k = 0; k < 128; k += 8) {
            float w0 = Wl[(k + 0) * 64 + lane];
            float w1 = Wl[(k + 1) * 64 + lane];
            float w2 = Wl[(k + 2) * 64 + lane];
            float w3 = Wl[(k + 3) * 64 + lane];
            float w4 = Wl[(k + 4) * 64 + lane];
            float w5 = Wl[(k + 5) * 64 + lane];
            float w6 = Wl[(k + 6) * 64 + lane];
            float w7 = Wl[(k + 7) * 64 + lane];
#pragma unroll
            for (int i = 0; i < 16; ++i) {
                uint4 q = *(const uint4*)(rowp[i] + k0 + k);
                acc[i] = fmaf(bflo(q.x), w0, acc[i]);
                acc[i] = fmaf(bfhi(q.x), w1, acc[i]);
                acc[i] = fmaf(bflo(q.y), w2, acc[i]);
                acc[i] = fmaf(bfhi(q.y), w3, acc[i]);
                acc[i] = fmaf(bflo(q.z), w4, acc[i]);
                acc[i] = fmaf(bfhi(q.z), w5, acc[i]);
                acc[i] = fmaf(bflo(q.w), w6, acc[i]);
                acc[i] = fmaf(bfhi(q.w), w7, acc[i]);
            }
        }
    }
#pragma unroll
    for (int i = 0; i < 16; ++i) {
        int r = r0 + i;
        if (r < n_rows) H1[(size_t)r * 64 + lane] = fmaxf(acc[i], 0.f);
    }
}

// ---------------------------------------------------------------------------
// Fused last two layers: z = H1@W2 + b2 (no relu); out = z@W3 + b3
// ---------------------------------------------------------------------------
__global__ __launch_bounds__(256) void mlp23(const float* __restrict__ H1,
                                             const float* __restrict__ W2,
                                             const float* __restrict__ b2,
                                             const float* __restrict__ W3,
                                             const float* __restrict__ b3,
                                             float* __restrict__ out) {
    __shared__ float Wl[64 * 32];
    __shared__ float w3l[32];
    __shared__ float b2l[32];
    int tid = threadIdx.x;
    for (int i = tid; i < 64 * 32; i += 256) Wl[i] = W2[i];
    if (tid < 32) { w3l[tid] = W3[tid]; b2l[tid] = b2[tid]; }
    __syncthreads();

    int lane = tid & 63;
    int wave = tid >> 6;
    int half = lane >> 5;
    int k = lane & 31;
    int gpair = blockIdx.x * 4 + wave;
    int npairs = gridDim.x * 4;
    float b3v = b3[0];
    for (int p = gpair; p * 2 < BATCH; p += npairs) {
        int r = p * 2 + half;
        float acc = b2l[k];
#pragma unroll
        for (int j = 0; j < 64; ++j)
            acc += H1[(size_t)r * 64 + j] * Wl[j * 32 + k];
        acc = acc * w3l[k];
#pragma unroll
        for (int off = 16; off; off >>= 1)
            acc += __shfl_xor(acc, off, 64);
        if (k == 0) out[r] = acc + b3v;
    }
}

// ---------------------------------------------------------------------------
extern "C" void kernel_launch(void* const* d_in, const int* in_sizes, int n_in,
                              void* d_out, int out_size, void* d_ws, size_t ws_size,
                              hipStream_t stream) {
    const int*   userIdx = (const int*)  d_in[0];
    const int*   itemIdx = (const int*)  d_in[1];
    const int*   lap_rows= (const int*)  d_in[2];
    const int*   lap_cols= (const int*)  d_in[3];
    const float* lap_vals= (const float*)d_in[4];
    const float* uEmb    = (const float*)d_in[5];
    const float* iEmb    = (const float*)d_in[6];
    const float* gW0     = (const float*)d_in[7];
    const float* gb0     = (const float*)d_in[8];
    const float* gW1     = (const float*)d_in[9];
    const float* gb1     = (const float*)d_in[10];
    const float* W1      = (const float*)d_in[11];
    const float* b1      = (const float*)d_in[12];
    const float* W2      = (const float*)d_in[13];
    const float* b2      = (const float*)d_in[14];
    const float* W3      = (const float*)d_in[15];
    const float* b3      = (const float*)d_in[16];
    float* out = (float*)d_out;

    const size_t NF = (size_t)N_NODES * EMB;              // 9.6M elements
    char* w = (char*)d_ws;
    unsigned short* bufA = (unsigned short*)w;            // feat0h/feat1h (19.2 MB)
    unsigned short* bufB = bufA + NF;                     // feat2h (19.2 MB)
    char*  region3 = (char*)(bufB + NF);                  // 38.4 MB multi-use
    // region3 first half: Zh while layers run, then E/H1 (Zh dead after spmm2)
    unsigned short* Zh = (unsigned short*)region3;        // Z table (19.2 MB)
    unsigned short* E  = (unsigned short*)region3;        // [BATCH,384] bf16 (12.6 MB)
    float* H1 = (float*)(E + (size_t)BATCH * D_CAT);      // [BATCH,64] fp32
    // pv in region3 second half: lives through both bucket_spmm calls
    int2*  pv      = (int2*)(region3 + NF * sizeof(float)); // 19.2 MB
    int*   boffs   = (int*)(pv + NNZ);                    // NBUCK+1 (immutable)
    int*   gtails  = boffs + (NBUCK + 1);                 // NBUCK (mutable tails)
    int*   bcnt    = gtails + NBUCK;                      // NBUCK

    const int ms_grid   = (NNZ + EPB - 1) / EPB;          // 293
    const int gemm_grid = (N_NODES + 63) / 64;            // 2344
    const int cvt_grid  = (int)((NF / 4 + 255) / 256);    // 9375

    // ---- Build bucketed edge list (shared by both layers)
    hipMemsetAsync(bcnt, 0, NBUCK * sizeof(int), stream);
    bucket_hist<<<128, 1024, 0, stream>>>(lap_rows, bcnt, NNZ);
    bucket_scan<<<1, 1024, 0, stream>>>(bcnt, boffs, gtails, NNZ);
    coarse_multisplit<<<ms_grid, 1024, 0, stream>>>(lap_rows, lap_cols, lap_vals,
                                                    gtails, pv, NNZ);

    // ---- feat0h = bf16(concat(uEmb, iEmb))
    cvt_feat0<<<cvt_grid, 256, 0, stream>>>((const float4*)uEmb, NUM_USERS * EMB / 4,
                                            (const float4*)iEmb, NUM_ITEMS * EMB / 4,
                                            (ushort4*)bufA);

    // ---- Layer 1: Z = feat0@gW0 ; feat1 = relu((L+I)Z + gb0)
    gemm_table_bf16<<<gemm_grid, 256, 0, stream>>>((const unsigned*)bufA, gW0, Zh, N_NODES);
    bucket_spmm<<<NBUCK, 512, 0, stream>>>(boffs, pv, (const unsigned*)Zh,
                                           gb0, (unsigned*)bufA);

    // ---- Layer 2: Z = feat1@gW1 ; feat2 = relu((L+I)Z + gb1)
    gemm_table_bf16<<<gemm_grid, 256, 0, stream>>>((const unsigned*)bufA, gW1, Zh, N_NODES);
    bucket_spmm<<<NBUCK, 512, 0, stream>>>(boffs, pv, (const unsigned*)Zh,
                                           gb1, (unsigned*)bufB);

    // ---- Gather per-sample concatenated features (E overlays Zh; Zh dead)
    gather_e<<<BATCH, 384, 0, stream>>>(userIdx, itemIdx, uEmb, iEmb, bufA, bufB, E);

    // ---- MLP
    gemm384_bf16_relu<<<(BATCH + 63) / 64, 256, 0, stream>>>(E, W1, b1, H1, BATCH);
    mlp23<<<512, 256, 0, stream>>>(H1, W2, b2, W3, b3, out);
}

// Round 11
// 563.481 us; speedup vs baseline: 4.2668x; 4.2668x over previous
//
#include <hip/hip_runtime.h>
#include <hip/hip_bf16.h>

// Problem constants (from reference)
#define NUM_USERS 100000
#define NUM_ITEMS 50000
#define N_NODES   150000   // NUM_USERS + NUM_ITEMS
#define EMB       64
#define NNZ       2400000
#define BATCH     16384
#define D_CAT     384      // EMB*3*2
#define BSHIFT    8        // 256 rows per bucket: multisplit segment ~2 lines
#define NBUCK     ((N_NODES + 255) >> 8)   // 586
#define EPB       8192     // edges per multisplit block

// ---- bf16 helpers (bit-level, RN-even for f32->bf16) -----------------------
__device__ __forceinline__ unsigned short f2bf(float f) {
    unsigned u = __float_as_uint(f);
    unsigned r = u + 0x7fffu + ((u >> 16) & 1u);
    return (unsigned short)(r >> 16);
}
__device__ __forceinline__ float bflo(unsigned u) { return __uint_as_float(u << 16); }
__device__ __forceinline__ float bfhi(unsigned u) { return __uint_as_float(u & 0xffff0000u); }

// ---------------------------------------------------------------------------
// Bucket histogram, LDS-aggregated (one global atomic per non-empty bucket
// per block; round-8 lesson: device atomics are memory-side ~32 B each).
// ---------------------------------------------------------------------------
__global__ __launch_bounds__(1024) void bucket_hist(const int* __restrict__ rows,
                                                    int* __restrict__ bcnt, int nnz) {
    __shared__ int h[NBUCK];
    int tid = threadIdx.x;
    for (int i = tid; i < NBUCK; i += 1024) h[i] = 0;
    __syncthreads();
    for (int i = blockIdx.x * 1024 + tid; i < nnz; i += gridDim.x * 1024)
        atomicAdd(&h[rows[i] >> BSHIFT], 1);
    __syncthreads();
    for (int i = tid; i < NBUCK; i += 1024) {
        int c = h[i];
        if (c) atomicAdd(&bcnt[i], c);
    }
}

// ---------------------------------------------------------------------------
// Exclusive scan over the 586 bucket counts (single block, 1 elem/thread).
// Emits boffs (+sentinel) and gtails (mutable copy for the multisplit).
// ---------------------------------------------------------------------------
__global__ __launch_bounds__(1024) void bucket_scan(const int* __restrict__ bcnt,
                                                    int* __restrict__ boffs,
                                                    int* __restrict__ gtails, int nnz) {
    __shared__ int s[1024];
    int t = threadIdx.x;
    int x = (t < NBUCK) ? bcnt[t] : 0;
    s[t] = x;
    __syncthreads();
#pragma unroll
    for (int off = 1; off < 1024; off <<= 1) {
        int v = (t >= off) ? s[t - off] : 0;
        __syncthreads();
        s[t] += v;
        __syncthreads();
    }
    if (t < NBUCK) {
        int e = s[t] - x;
        boffs[t] = e;
        gtails[t] = e;
    }
    if (t == 0) boffs[NBUCK] = nnz;
}

// ---------------------------------------------------------------------------
// LDS-staged multisplit into 256-row buckets. Per-block per-bucket segment is
// ~14 edges (~2 cache lines) -> near-single-CU line ownership (round-9's
// 32-row buckets gave 1.75-edge segments -> ~4 writers/line -> 80 MB wb).
// pv payload: .x = (r_local<<18) | col  (rl<256, col<2^18), .y = val
// ---------------------------------------------------------------------------
__global__ __launch_bounds__(1024) void coarse_multisplit(const int* __restrict__ rows,
                                                          const int* __restrict__ cols,
                                                          const float* __restrict__ vals,
                                                          int* __restrict__ gtails,
                                                          int2* __restrict__ pv, int nnz) {
    __shared__ int hcnt[NBUCK];
    int tid = threadIdx.x;
    int e0 = blockIdx.x * EPB;
    int e1 = e0 + EPB < nnz ? e0 + EPB : nnz;

    for (int i = tid; i < NBUCK; i += 1024) hcnt[i] = 0;
    __syncthreads();
    for (int i = e0 + tid; i < e1; i += 1024)
        atomicAdd(&hcnt[rows[i] >> BSHIFT], 1);
    __syncthreads();
    for (int i = tid; i < NBUCK; i += 1024) {
        int c = hcnt[i];
        if (c) hcnt[i] = atomicAdd(&gtails[i], c);   // global base for this block
    }
    __syncthreads();
    for (int i = e0 + tid; i < e1; i += 1024) {
        int r = rows[i];
        int pos = atomicAdd(&hcnt[r >> BSHIFT], 1);  // LDS bump from global base
        pv[pos] = make_int2(((r & 255) << 18) | cols[i], __float_as_int(vals[i]));
    }
}

// ---------------------------------------------------------------------------
// Fine scatter within a 256-row bucket + row_ptr production. INT LDS atomics
// at high block count (proven fast in round 9; round-10's fused-LDS-float-acc
// spmm was the failure, not this pattern). One block per bucket: count rows,
// in-block scan (Hillis-Steele over 256), write row_ptr coalesced, scatter
// into the bucket's 16 KB window (single-CU writer).
// ---------------------------------------------------------------------------
__global__ __launch_bounds__(512) void fine_scatter(const int* __restrict__ boffs,
                                                    const int2* __restrict__ pv,
                                                    int2* __restrict__ packed,
                                                    int* __restrict__ row_ptr, int nnz) {
    __shared__ int rcnt[256];
    __shared__ int loff[256];
    int b = blockIdx.x;
    int tid = threadIdx.x;
    int lo = boffs[b], hi = boffs[b + 1];
    int r0 = b << BSHIFT;
    int nr = N_NODES - r0; if (nr > 256) nr = 256;

    if (tid < 256) rcnt[tid] = 0;
    __syncthreads();
    for (int i = lo + tid; i < hi; i += 512)
        atomicAdd(&rcnt[pv[i].x >> 18], 1);
    __syncthreads();
    if (tid < 256) loff[tid] = rcnt[tid];
    __syncthreads();
#pragma unroll
    for (int off = 1; off < 256; off <<= 1) {
        int v = (tid < 256 && tid >= off) ? loff[tid - off] : 0;
        __syncthreads();
        if (tid < 256) loff[tid] += v;
        __syncthreads();
    }
    if (tid < 256) {
        int e = lo + loff[tid] - rcnt[tid];    // exclusive prefix + bucket base
        loff[tid] = e;
        if (tid < nr) row_ptr[r0 + tid] = e;
    }
    if (b == 0 && tid == 0) row_ptr[N_NODES] = nnz;
    __syncthreads();
    for (int i = lo + tid; i < hi; i += 512) {
        int2 e = pv[i];
        int rl = e.x >> 18;
        int pos = atomicAdd(&loff[rl], 1);
        packed[pos] = make_int2(e.x & 0x3FFFF, e.y);
    }
}

// ---------------------------------------------------------------------------
// Convert concat(uEmb,iEmb) fp32 -> bf16 table (4 elems / thread)
// ---------------------------------------------------------------------------
__global__ __launch_bounds__(256) void cvt_feat0(const float4* __restrict__ a, int na4,
                                                 const float4* __restrict__ b, int nb4,
                                                 ushort4* __restrict__ dst) {
    int i = blockIdx.x * 256 + threadIdx.x;
    if (i >= na4 + nb4) return;
    float4 v = (i < na4) ? a[i] : b[i - na4];
    ushort4 o;
    o.x = f2bf(v.x); o.y = f2bf(v.y); o.z = f2bf(v.z); o.w = f2bf(v.w);
    dst[i] = o;
}

// ---------------------------------------------------------------------------
// Z = X @ W   (X: bf16 table [n x 64], W: fp32 [64 x 64], Z: bf16 [n x 64])
// ((L+I)X)W == (L+I)(XW): GEMM before spmm; all inner-loop reads are LDS.
// ---------------------------------------------------------------------------
__global__ __launch_bounds__(256) void gemm_table_bf16(const unsigned* __restrict__ Xh,
                                                       const float* __restrict__ W,
                                                       unsigned short* __restrict__ Zh,
                                                       int n_rows) {
    __shared__ float Wl[64 * 64];        // 16 KB
    __shared__ uint4 Xl4[64 * 8];        // 8 KB: 64 rows x 32 uints (bf16x2)
    int tid = threadIdx.x;
    int lane = tid & 63;
    int wave = tid >> 6;
    int r0 = blockIdx.x * 64;
    int nr = n_rows - r0; if (nr > 64) nr = 64;

    for (int i = tid; i < 64 * 64; i += 256) Wl[i] = W[i];
    const uint4* Xg4 = (const uint4*)(Xh + (size_t)r0 * 32);
    for (int i = tid; i < nr * 8; i += 256) Xl4[i] = Xg4[i];
    __syncthreads();

    const unsigned* Xl = (const unsigned*)Xl4;
    int rbase = wave * 16;
    float acc[16];
#pragma unroll
    for (int i = 0; i < 16; ++i) acc[i] = 0.f;

#pragma unroll 1
    for (int kc = 0; kc < 8; ++kc) {     // 8 k-values per chunk
        float w0 = Wl[(kc * 8 + 0) * 64 + lane];
        float w1 = Wl[(kc * 8 + 1) * 64 + lane];
        float w2 = Wl[(kc * 8 + 2) * 64 + lane];
        float w3 = Wl[(kc * 8 + 3) * 64 + lane];
        float w4 = Wl[(kc * 8 + 4) * 64 + lane];
        float w5 = Wl[(kc * 8 + 5) * 64 + lane];
        float w6 = Wl[(kc * 8 + 6) * 64 + lane];
        float w7 = Wl[(kc * 8 + 7) * 64 + lane];
#pragma unroll
        for (int i = 0; i < 16; ++i) {
            uint4 q = *(const uint4*)&Xl[(rbase + i) * 32 + kc * 4];  // broadcast
            acc[i] = fmaf(bflo(q.x), w0, acc[i]);
            acc[i] = fmaf(bfhi(q.x), w1, acc[i]);
            acc[i] = fmaf(bflo(q.y), w2, acc[i]);
            acc[i] = fmaf(bfhi(q.y), w3, acc[i]);
            acc[i] = fmaf(bflo(q.z), w4, acc[i]);
            acc[i] = fmaf(bfhi(q.z), w5, acc[i]);
            acc[i] = fmaf(bflo(q.w), w6, acc[i]);
            acc[i] = fmaf(bfhi(q.w), w7, acc[i]);
        }
    }
#pragma unroll
    for (int i = 0; i < 16; ++i) {
        int r = r0 + rbase + i;
        if (r < n_rows) Zh[(size_t)r * 64 + lane] = f2bf(acc[i]);
    }
}

// ---------------------------------------------------------------------------
// SPMM + bias + relu: out[r] = relu( Z[r] + sum_edges v * Z[c] + bias ), bf16.
// One wave per row; half-wave per edge; register accumulation (proven in
// rounds 8-9; round-10's LDS-accumulator variant was 12x slower).
// ---------------------------------------------------------------------------
__global__ __launch_bounds__(256) void spmm_bias_relu(const int* __restrict__ row_ptr,
                                                      const int2* __restrict__ packed,
                                                      const unsigned* __restrict__ zh,  // bf16x2, 32/row
                                                      const float* __restrict__ bias,   // [64] fp32
                                                      unsigned* __restrict__ outh,      // bf16x2, 32/row
                                                      int n_rows) {
    int tid = threadIdx.x;
    int lane = tid & 63;
    int wave = tid >> 6;
    int half = lane >> 5;
    int k = lane & 31;
    int r = blockIdx.x * 4 + wave;
    if (r >= n_rows) return;

    unsigned su = zh[(size_t)r * 32 + k];
    float2 acc;
    acc.x = half ? 0.f : bflo(su);
    acc.y = half ? 0.f : bfhi(su);

    int e = row_ptr[r] + half;
    int end = row_ptr[r + 1];
    for (; e + 6 < end; e += 8) {
        int2 p0 = packed[e + 0];
        int2 p1 = packed[e + 2];
        int2 p2 = packed[e + 4];
        int2 p3 = packed[e + 6];
        unsigned x0 = zh[(size_t)p0.x * 32 + k];
        unsigned x1 = zh[(size_t)p1.x * 32 + k];
        unsigned x2 = zh[(size_t)p2.x * 32 + k];
        unsigned x3 = zh[(size_t)p3.x * 32 + k];
        float v0 = __int_as_float(p0.y), v1 = __int_as_float(p1.y);
        float v2 = __int_as_float(p2.y), v3 = __int_as_float(p3.y);
        acc.x = fmaf(v0, bflo(x0), acc.x); acc.y = fmaf(v0, bfhi(x0), acc.y);
        acc.x = fmaf(v1, bflo(x1), acc.x); acc.y = fmaf(v1, bfhi(x1), acc.y);
        acc.x = fmaf(v2, bflo(x2), acc.x); acc.y = fmaf(v2, bfhi(x2), acc.y);
        acc.x = fmaf(v3, bflo(x3), acc.x); acc.y = fmaf(v3, bfhi(x3), acc.y);
    }
    for (; e < end; e += 2) {
        int2 p = packed[e];
        unsigned x = zh[(size_t)p.x * 32 + k];
        float v = __int_as_float(p.y);
        acc.x = fmaf(v, bflo(x), acc.x);
        acc.y = fmaf(v, bfhi(x), acc.y);
    }

    acc.x += __shfl_xor(acc.x, 32, 64);
    acc.y += __shfl_xor(acc.y, 32, 64);
    if (!half) {
        float2 bv = *(const float2*)(bias + 2 * k);
        float ox = fmaxf(acc.x + bv.x, 0.f);
        float oy = fmaxf(acc.y + bv.y, 0.f);
        outh[(size_t)r * 32 + k] = ((unsigned)f2bf(oy) << 16) | (unsigned)f2bf(ox);
    }
}

// ---------------------------------------------------------------------------
// Gather concatenated per-sample features -> bf16 E (one 384-thread block/row)
// ---------------------------------------------------------------------------
__global__ __launch_bounds__(384) void gather_e(const int* __restrict__ userIdx,
                                                const int* __restrict__ itemIdx,
                                                const float* __restrict__ uEmb,
                                                const float* __restrict__ iEmb,
                                                const unsigned short* __restrict__ feat1h,
                                                const unsigned short* __restrict__ feat2h,
                                                unsigned short* __restrict__ E) {
    int b = blockIdx.x;
    int j = threadIdx.x;          // 0..383
    int half = j >= 192;
    int jj = half ? (j - 192) : j;
    int seg = jj >> 6;
    int k = jj & 63;
    unsigned short v;
    if (half == 0) {
        int u = userIdx[b];
        if (seg == 0)      v = f2bf(uEmb[(size_t)u * 64 + k]);
        else if (seg == 1) v = feat1h[(size_t)u * 64 + k];
        else               v = feat2h[(size_t)u * 64 + k];
    } else {
        int it = itemIdx[b];
        if (seg == 0)      v = f2bf(iEmb[(size_t)it * 64 + k]);
        else if (seg == 1) v = feat1h[(size_t)(it + NUM_USERS) * 64 + k];
        else               v = feat2h[(size_t)(it + NUM_USERS) * 64 + k];
    }
    E[(size_t)b * D_CAT + j] = v;
}

// ---------------------------------------------------------------------------
// H1[r][c] = relu( b1[c] + sum_{k<384} E[r][k] * W1[k][c] ), E bf16.
// ---------------------------------------------------------------------------
__global__ __launch_bounds__(256) void gemm384_bf16_relu(const unsigned short* __restrict__ E,
                                                         const float* __restrict__ W,
                                                         const float* __restrict__ bia,
                                                         float* __restrict__ H1,
                                                         int n_rows) {
    __shared__ float Wl[128 * 64];   // 32 KB
    int tid = threadIdx.x;
    int lane = tid & 63;
    int wave = tid >> 6;
    int r0 = blockIdx.x * 64 + wave * 16;
    int last = n_rows - 1;

    const unsigned short* rowp[16];
#pragma unroll
    for (int i = 0; i < 16; ++i) {
        int r = r0 + i;
        r = r > last ? last : r;
        rowp[i] = E + (size_t)r * D_CAT;
    }
    float acc[16];
    float bv = bia[lane];
#pragma unroll
    for (int i = 0; i < 16; ++i) acc[i] = bv;

    for (int k0 = 0; k0 < D_CAT; k0 += 128) {
        if (k0) __syncthreads();
        for (int i = tid; i < 128 * 64; i += 256) Wl[i] = W[k0 * 64 + i];
        __syncthreads();
#pragma unroll 1
        for (int k = 0; k < 128; k += 8) {
            float w0 = Wl[(k + 0) * 64 + lane];
            float w1 = Wl[(k + 1) * 64 + lane];
            float w2 = Wl[(k + 2) * 64 + lane];
            float w3 = Wl[(k + 3) * 64 + lane];
            float w4 = Wl[(k + 4) * 64 + lane];
            float w5 = Wl[(k + 5) * 64 + lane];
            float w6 = Wl[(k + 6) * 64 + lane];
            float w7 = Wl[(k + 7) * 64 + lane];
#pragma unroll
            for (int i = 0; i < 16; ++i) {
                uint4 q = *(const uint4*)(rowp[i] + k0 + k);
                acc[i] = fmaf(bflo(q.x), w0, acc[i]);
                acc[i] = fmaf(bfhi(q.x), w1, acc[i]);
                acc[i] = fmaf(bflo(q.y), w2, acc[i]);
                acc[i] = fmaf(bfhi(q.y), w3, acc[i]);
                acc[i] = fmaf(bflo(q.z), w4, acc[i]);
                acc[i] = fmaf(bfhi(q.z), w5, acc[i]);
                acc[i] = fmaf(bflo(q.w), w6, acc[i]);
                acc[i] = fmaf(bfhi(q.w), w7, acc[i]);
            }
        }
    }
#pragma unroll
    for (int i = 0; i < 16; ++i) {
        int r = r0 + i;
        if (r < n_rows) H1[(size_t)r * 64 + lane] = fmaxf(acc[i], 0.f);
    }
}

// ---------------------------------------------------------------------------
// Fused last two layers: z = H1@W2 + b2 (no relu); out = z@W3 + b3
// ---------------------------------------------------------------------------
__global__ __launch_bounds__(256) void mlp23(const float* __restrict__ H1,
                                             const float* __restrict__ W2,
                                             const float* __restrict__ b2,
                                             const float* __restrict__ W3,
                                             const float* __restrict__ b3,
                                             float* __restrict__ out) {
    __shared__ float Wl[64 * 32];
    __shared__ float w3l[32];
    __shared__ float b2l[32];
    int tid = threadIdx.x;
    for (int i = tid; i < 64 * 32; i += 256) Wl[i] = W2[i];
    if (tid < 32) { w3l[tid] = W3[tid]; b2l[tid] = b2[tid]; }
    __syncthreads();

    int lane = tid & 63;
    int wave = tid >> 6;
    int half = lane >> 5;
    int k = lane & 31;
    int gpair = blockIdx.x * 4 + wave;
    int npairs = gridDim.x * 4;
    float b3v = b3[0];
    for (int p = gpair; p * 2 < BATCH; p += npairs) {
        int r = p * 2 + half;
        float acc = b2l[k];
#pragma unroll
        for (int j = 0; j < 64; ++j)
            acc += H1[(size_t)r * 64 + j] * Wl[j * 32 + k];
        acc = acc * w3l[k];
#pragma unroll
        for (int off = 16; off; off >>= 1)
            acc += __shfl_xor(acc, off, 64);
        if (k == 0) out[r] = acc + b3v;
    }
}

// ---------------------------------------------------------------------------
extern "C" void kernel_launch(void* const* d_in, const int* in_sizes, int n_in,
                              void* d_out, int out_size, void* d_ws, size_t ws_size,
                              hipStream_t stream) {
    const int*   userIdx = (const int*)  d_in[0];
    const int*   itemIdx = (const int*)  d_in[1];
    const int*   lap_rows= (const int*)  d_in[2];
    const int*   lap_cols= (const int*)  d_in[3];
    const float* lap_vals= (const float*)d_in[4];
    const float* uEmb    = (const float*)d_in[5];
    const float* iEmb    = (const float*)d_in[6];
    const float* gW0     = (const float*)d_in[7];
    const float* gb0     = (const float*)d_in[8];
    const float* gW1     = (const float*)d_in[9];
    const float* gb1     = (const float*)d_in[10];
    const float* W1      = (const float*)d_in[11];
    const float* b1      = (const float*)d_in[12];
    const float* W2      = (const float*)d_in[13];
    const float* b2      = (const float*)d_in[14];
    const float* W3      = (const float*)d_in[15];
    const float* b3      = (const float*)d_in[16];
    float* out = (float*)d_out;

    const size_t NF = (size_t)N_NODES * EMB;              // 9.6M elements
    char* w = (char*)d_ws;
    unsigned short* bufA = (unsigned short*)w;            // feat0h/feat1h (19.2 MB)
    unsigned short* bufB = bufA + NF;                     // feat2h (19.2 MB)
    char*  region3 = (char*)(bufB + NF);                  // 38.4 MB multi-use
    // region3 first half: pv during CSR build, then Zh, then E/H1
    int2*  pv      = (int2*)region3;                      // 19.2 MB (dead after fine_scatter)
    unsigned short* Zh = (unsigned short*)region3;        // Z table (19.2 MB)
    unsigned short* E  = (unsigned short*)region3;        // [BATCH,384] bf16 (12.6 MB)
    float* H1 = (float*)(E + (size_t)BATCH * D_CAT);      // [BATCH,64] fp32
    // region3 second half: packed lives through both spmm calls
    int2*  packed  = (int2*)(region3 + NF * sizeof(float)); // 19.2 MB
    int*   row_ptr = (int*)(packed + NNZ);                // N_NODES+1
    int*   boffs   = row_ptr + (N_NODES + 1);             // NBUCK+1 (immutable)
    int*   gtails  = boffs + (NBUCK + 1);                 // NBUCK (mutable tails)
    int*   bcnt    = gtails + NBUCK;                      // NBUCK

    const int ms_grid   = (NNZ + EPB - 1) / EPB;          // 293
    const int spmm_grid = (N_NODES + 3) / 4;              // 37500
    const int gemm_grid = (N_NODES + 63) / 64;            // 2344
    const int cvt_grid  = (int)((NF / 4 + 255) / 256);    // 9375

    // ---- Build bucketed CSR (shared by both layers)
    hipMemsetAsync(bcnt, 0, NBUCK * sizeof(int), stream);
    bucket_hist<<<128, 1024, 0, stream>>>(lap_rows, bcnt, NNZ);
    bucket_scan<<<1, 1024, 0, stream>>>(bcnt, boffs, gtails, NNZ);
    coarse_multisplit<<<ms_grid, 1024, 0, stream>>>(lap_rows, lap_cols, lap_vals,
                                                    gtails, pv, NNZ);
    fine_scatter<<<NBUCK, 512, 0, stream>>>(boffs, pv, packed, row_ptr, NNZ);

    // ---- feat0h = bf16(concat(uEmb, iEmb))
    cvt_feat0<<<cvt_grid, 256, 0, stream>>>((const float4*)uEmb, NUM_USERS * EMB / 4,
                                            (const float4*)iEmb, NUM_ITEMS * EMB / 4,
                                            (ushort4*)bufA);

    // ---- Layer 1: Z = feat0@gW0 ; feat1 = relu((L+I)Z + gb0)
    gemm_table_bf16<<<gemm_grid, 256, 0, stream>>>((const unsigned*)bufA, gW0, Zh, N_NODES);
    spmm_bias_relu<<<spmm_grid, 256, 0, stream>>>(row_ptr, packed, (const unsigned*)Zh,
                                                  gb0, (unsigned*)bufA, N_NODES);

    // ---- Layer 2: Z = feat1@gW1 ; feat2 = relu((L+I)Z + gb1)
    gemm_table_bf16<<<gemm_grid, 256, 0, stream>>>((const unsigned*)bufA, gW1, Zh, N_NODES);
    spmm_bias_relu<<<spmm_grid, 256, 0, stream>>>(row_ptr, packed, (const unsigned*)Zh,
                                                  gb1, (unsigned*)bufB, N_NODES);

    // ---- Gather per-sample concatenated features (E overlays Zh; Zh dead)
    gather_e<<<BATCH, 384, 0, stream>>>(userIdx, itemIdx, uEmb, iEmb, bufA, bufB, E);

    // ---- MLP
    gemm384_bf16_relu<<<(BATCH + 63) / 64, 256, 0, stream>>>(E, W1, b1, H1, BATCH);
    mlp23<<<512, 256, 0, stream>>>(H1, W2, b2, W3, b3, out);
}

// Round 12
// 519.735 us; speedup vs baseline: 4.6259x; 1.0842x over previous
//
#include <hip/hip_runtime.h>
#include <hip/hip_bf16.h>

// Problem constants (from reference)
#define NUM_USERS 100000
#define NUM_ITEMS 50000
#define N_NODES   150000   // NUM_USERS + NUM_ITEMS
#define EMB       64
#define NNZ       2400000
#define BATCH     16384
#define D_CAT     384      // EMB*3*2
#define BSHIFT    8        // 256 rows per bucket: multisplit segment ~2 lines
#define NBUCK     ((N_NODES + 255) >> 8)   // 586
#define EPB       8192     // edges per multisplit block

// ---- bf16 helpers (bit-level, RN-even for f32->bf16) -----------------------
__device__ __forceinline__ unsigned short f2bf(float f) {
    unsigned u = __float_as_uint(f);
    unsigned r = u + 0x7fffu + ((u >> 16) & 1u);
    return (unsigned short)(r >> 16);
}
__device__ __forceinline__ float bflo(unsigned u) { return __uint_as_float(u << 16); }
__device__ __forceinline__ float bfhi(unsigned u) { return __uint_as_float(u & 0xffff0000u); }

// ---------------------------------------------------------------------------
// Bucket histogram, LDS-aggregated (one global atomic per non-empty bucket
// per block; round-8 lesson: device atomics are memory-side ~32 B each).
// ---------------------------------------------------------------------------
__global__ __launch_bounds__(1024) void bucket_hist(const int* __restrict__ rows,
                                                    int* __restrict__ bcnt, int nnz) {
    __shared__ int h[NBUCK];
    int tid = threadIdx.x;
    for (int i = tid; i < NBUCK; i += 1024) h[i] = 0;
    __syncthreads();
    for (int i = blockIdx.x * 1024 + tid; i < nnz; i += gridDim.x * 1024)
        atomicAdd(&h[rows[i] >> BSHIFT], 1);
    __syncthreads();
    for (int i = tid; i < NBUCK; i += 1024) {
        int c = h[i];
        if (c) atomicAdd(&bcnt[i], c);
    }
}

// ---------------------------------------------------------------------------
// Exclusive scan over the 586 bucket counts (single block, 1 elem/thread).
// Emits boffs (+sentinel) and gtails (mutable copy for the multisplit).
// ---------------------------------------------------------------------------
__global__ __launch_bounds__(1024) void bucket_scan(const int* __restrict__ bcnt,
                                                    int* __restrict__ boffs,
                                                    int* __restrict__ gtails, int nnz) {
    __shared__ int s[1024];
    int t = threadIdx.x;
    int x = (t < NBUCK) ? bcnt[t] : 0;
    s[t] = x;
    __syncthreads();
#pragma unroll
    for (int off = 1; off < 1024; off <<= 1) {
        int v = (t >= off) ? s[t - off] : 0;
        __syncthreads();
        s[t] += v;
        __syncthreads();
    }
    if (t < NBUCK) {
        int e = s[t] - x;
        boffs[t] = e;
        gtails[t] = e;
    }
    if (t == 0) boffs[NBUCK] = nnz;
}

// ---------------------------------------------------------------------------
// LDS-staged multisplit into 256-row buckets (~14-edge per-block segments ≈
// 2 cache lines -> near-single-CU line ownership).
// pv payload: .x = (r_local<<18) | col  (rl<256, col<2^18), .y = val
// ---------------------------------------------------------------------------
__global__ __launch_bounds__(1024) void coarse_multisplit(const int* __restrict__ rows,
                                                          const int* __restrict__ cols,
                                                          const float* __restrict__ vals,
                                                          int* __restrict__ gtails,
                                                          int2* __restrict__ pv, int nnz) {
    __shared__ int hcnt[NBUCK];
    int tid = threadIdx.x;
    int e0 = blockIdx.x * EPB;
    int e1 = e0 + EPB < nnz ? e0 + EPB : nnz;

    for (int i = tid; i < NBUCK; i += 1024) hcnt[i] = 0;
    __syncthreads();
    for (int i = e0 + tid; i < e1; i += 1024)
        atomicAdd(&hcnt[rows[i] >> BSHIFT], 1);
    __syncthreads();
    for (int i = tid; i < NBUCK; i += 1024) {
        int c = hcnt[i];
        if (c) hcnt[i] = atomicAdd(&gtails[i], c);   // global base for this block
    }
    __syncthreads();
    for (int i = e0 + tid; i < e1; i += 1024) {
        int r = rows[i];
        int pos = atomicAdd(&hcnt[r >> BSHIFT], 1);  // LDS bump from global base
        pv[pos] = make_int2(((r & 255) << 18) | cols[i], __float_as_int(vals[i]));
    }
}

// ---------------------------------------------------------------------------
// Fine scatter within a 256-row bucket + row_ptr production (int LDS atomics,
// proven pattern). 1024 threads (512 was parallelism-starved at 2.3 blk/CU).
// ---------------------------------------------------------------------------
__global__ __launch_bounds__(1024) void fine_scatter(const int* __restrict__ boffs,
                                                     const int2* __restrict__ pv,
                                                     int2* __restrict__ packed,
                                                     int* __restrict__ row_ptr, int nnz) {
    __shared__ int rcnt[256];
    __shared__ int loff[256];
    int b = blockIdx.x;
    int tid = threadIdx.x;
    int lo = boffs[b], hi = boffs[b + 1];
    int r0 = b << BSHIFT;
    int nr = N_NODES - r0; if (nr > 256) nr = 256;

    if (tid < 256) rcnt[tid] = 0;
    __syncthreads();
    for (int i = lo + tid; i < hi; i += 1024)
        atomicAdd(&rcnt[pv[i].x >> 18], 1);
    __syncthreads();
    if (tid < 256) loff[tid] = rcnt[tid];
    __syncthreads();
#pragma unroll
    for (int off = 1; off < 256; off <<= 1) {
        int v = (tid < 256 && tid >= off) ? loff[tid - off] : 0;
        __syncthreads();
        if (tid < 256) loff[tid] += v;
        __syncthreads();
    }
    if (tid < 256) {
        int e = lo + loff[tid] - rcnt[tid];    // exclusive prefix + bucket base
        loff[tid] = e;
        if (tid < nr) row_ptr[r0 + tid] = e;
    }
    if (b == 0 && tid == 0) row_ptr[N_NODES] = nnz;
    __syncthreads();
    for (int i = lo + tid; i < hi; i += 1024) {
        int2 e = pv[i];
        int rl = e.x >> 18;
        int pos = atomicAdd(&loff[rl], 1);
        packed[pos] = make_int2(e.x & 0x3FFFF, e.y);
    }
}

// ---------------------------------------------------------------------------
// Layer-1 table GEMM directly from fp32 embeddings (fuses the old cvt_feat0):
// Z = concat(uEmb,iEmb) @ W, output bf16. X tile staged in LDS as fp32.
// ---------------------------------------------------------------------------
__global__ __launch_bounds__(256) void gemm_table_f32(const float* __restrict__ uE,
                                                      const float* __restrict__ iE,
                                                      const float* __restrict__ W,
                                                      unsigned short* __restrict__ Zh,
                                                      int n_rows) {
    __shared__ float Wl[64 * 64];        // 16 KB
    __shared__ float Xf[64 * 64];        // 16 KB
    int tid = threadIdx.x;
    int lane = tid & 63;
    int wave = tid >> 6;
    int r0 = blockIdx.x * 64;
    int last = n_rows - 1;

    for (int i = tid; i < 64 * 64; i += 256) Wl[i] = W[i];
    for (int i = tid; i < 64 * 16; i += 256) {       // 1024 float4
        int row = i >> 4, q = i & 15;
        int r = r0 + row; r = r > last ? last : r;
        const float4* src = (r < NUM_USERS)
            ? (const float4*)(uE + (size_t)r * 64)
            : (const float4*)(iE + (size_t)(r - NUM_USERS) * 64);
        ((float4*)Xf)[i] = src[q];
    }
    __syncthreads();

    int rbase = wave * 16;
    float acc[16];
#pragma unroll
    for (int i = 0; i < 16; ++i) acc[i] = 0.f;

#pragma unroll 1
    for (int kc = 0; kc < 16; ++kc) {    // 4 k-values per chunk
        float w0 = Wl[(kc * 4 + 0) * 64 + lane];
        float w1 = Wl[(kc * 4 + 1) * 64 + lane];
        float w2 = Wl[(kc * 4 + 2) * 64 + lane];
        float w3 = Wl[(kc * 4 + 3) * 64 + lane];
#pragma unroll
        for (int i = 0; i < 16; ++i) {
            float4 q = ((const float4*)Xf)[(rbase + i) * 16 + kc];  // LDS broadcast
            acc[i] = fmaf(q.x, w0, acc[i]);
            acc[i] = fmaf(q.y, w1, acc[i]);
            acc[i] = fmaf(q.z, w2, acc[i]);
            acc[i] = fmaf(q.w, w3, acc[i]);
        }
    }
#pragma unroll
    for (int i = 0; i < 16; ++i) {
        int r = r0 + rbase + i;
        if (r < n_rows) Zh[(size_t)r * 64 + lane] = f2bf(acc[i]);
    }
}

// ---------------------------------------------------------------------------
// Layer-2 table GEMM from the bf16 feature table (unchanged from round 11).
// ---------------------------------------------------------------------------
__global__ __launch_bounds__(256) void gemm_table_bf16(const unsigned* __restrict__ Xh,
                                                       const float* __restrict__ W,
                                                       unsigned short* __restrict__ Zh,
                                                       int n_rows) {
    __shared__ float Wl[64 * 64];        // 16 KB
    __shared__ uint4 Xl4[64 * 8];        // 8 KB: 64 rows x 32 uints (bf16x2)
    int tid = threadIdx.x;
    int lane = tid & 63;
    int wave = tid >> 6;
    int r0 = blockIdx.x * 64;
    int nr = n_rows - r0; if (nr > 64) nr = 64;

    for (int i = tid; i < 64 * 64; i += 256) Wl[i] = W[i];
    const uint4* Xg4 = (const uint4*)(Xh + (size_t)r0 * 32);
    for (int i = tid; i < nr * 8; i += 256) Xl4[i] = Xg4[i];
    __syncthreads();

    const unsigned* Xl = (const unsigned*)Xl4;
    int rbase = wave * 16;
    float acc[16];
#pragma unroll
    for (int i = 0; i < 16; ++i) acc[i] = 0.f;

#pragma unroll 1
    for (int kc = 0; kc < 8; ++kc) {     // 8 k-values per chunk
        float w0 = Wl[(kc * 8 + 0) * 64 + lane];
        float w1 = Wl[(kc * 8 + 1) * 64 + lane];
        float w2 = Wl[(kc * 8 + 2) * 64 + lane];
        float w3 = Wl[(kc * 8 + 3) * 64 + lane];
        float w4 = Wl[(kc * 8 + 4) * 64 + lane];
        float w5 = Wl[(kc * 8 + 5) * 64 + lane];
        float w6 = Wl[(kc * 8 + 6) * 64 + lane];
        float w7 = Wl[(kc * 8 + 7) * 64 + lane];
#pragma unroll
        for (int i = 0; i < 16; ++i) {
            uint4 q = *(const uint4*)&Xl[(rbase + i) * 32 + kc * 4];  // broadcast
            acc[i] = fmaf(bflo(q.x), w0, acc[i]);
            acc[i] = fmaf(bfhi(q.x), w1, acc[i]);
            acc[i] = fmaf(bflo(q.y), w2, acc[i]);
            acc[i] = fmaf(bfhi(q.y), w3, acc[i]);
            acc[i] = fmaf(bflo(q.z), w4, acc[i]);
            acc[i] = fmaf(bfhi(q.z), w5, acc[i]);
            acc[i] = fmaf(bflo(q.w), w6, acc[i]);
            acc[i] = fmaf(bfhi(q.w), w7, acc[i]);
        }
    }
#pragma unroll
    for (int i = 0; i < 16; ++i) {
        int r = r0 + rbase + i;
        if (r < n_rows) Zh[(size_t)r * 64 + lane] = f2bf(acc[i]);
    }
}

// ---------------------------------------------------------------------------
// SPMM + bias + relu: out[r] = relu( Z[r] + sum_edges v * Z[c] + bias ), bf16.
// One wave per row; half-wave per edge; register accumulation (proven).
// ---------------------------------------------------------------------------
__global__ __launch_bounds__(256) void spmm_bias_relu(const int* __restrict__ row_ptr,
                                                      const int2* __restrict__ packed,
                                                      const unsigned* __restrict__ zh,  // bf16x2, 32/row
                                                      const float* __restrict__ bias,   // [64] fp32
                                                      unsigned* __restrict__ outh,      // bf16x2, 32/row
                                                      int n_rows) {
    int tid = threadIdx.x;
    int lane = tid & 63;
    int wave = tid >> 6;
    int half = lane >> 5;
    int k = lane & 31;
    int r = blockIdx.x * 4 + wave;
    if (r >= n_rows) return;

    unsigned su = zh[(size_t)r * 32 + k];
    float2 acc;
    acc.x = half ? 0.f : bflo(su);
    acc.y = half ? 0.f : bfhi(su);

    int e = row_ptr[r] + half;
    int end = row_ptr[r + 1];
    for (; e + 6 < end; e += 8) {
        int2 p0 = packed[e + 0];
        int2 p1 = packed[e + 2];
        int2 p2 = packed[e + 4];
        int2 p3 = packed[e + 6];
        unsigned x0 = zh[(size_t)p0.x * 32 + k];
        unsigned x1 = zh[(size_t)p1.x * 32 + k];
        unsigned x2 = zh[(size_t)p2.x * 32 + k];
        unsigned x3 = zh[(size_t)p3.x * 32 + k];
        float v0 = __int_as_float(p0.y), v1 = __int_as_float(p1.y);
        float v2 = __int_as_float(p2.y), v3 = __int_as_float(p3.y);
        acc.x = fmaf(v0, bflo(x0), acc.x); acc.y = fmaf(v0, bfhi(x0), acc.y);
        acc.x = fmaf(v1, bflo(x1), acc.x); acc.y = fmaf(v1, bfhi(x1), acc.y);
        acc.x = fmaf(v2, bflo(x2), acc.x); acc.y = fmaf(v2, bfhi(x2), acc.y);
        acc.x = fmaf(v3, bflo(x3), acc.x); acc.y = fmaf(v3, bfhi(x3), acc.y);
    }
    for (; e < end; e += 2) {
        int2 p = packed[e];
        unsigned x = zh[(size_t)p.x * 32 + k];
        float v = __int_as_float(p.y);
        acc.x = fmaf(v, bflo(x), acc.x);
        acc.y = fmaf(v, bfhi(x), acc.y);
    }

    acc.x += __shfl_xor(acc.x, 32, 64);
    acc.y += __shfl_xor(acc.y, 32, 64);
    if (!half) {
        float2 bv = *(const float2*)(bias + 2 * k);
        float ox = fmaxf(acc.x + bv.x, 0.f);
        float oy = fmaxf(acc.y + bv.y, 0.f);
        outh[(size_t)r * 32 + k] = ((unsigned)f2bf(oy) << 16) | (unsigned)f2bf(ox);
    }
}

// ---------------------------------------------------------------------------
// Gather concatenated per-sample features -> bf16 E (one 384-thread block/row)
// ---------------------------------------------------------------------------
__global__ __launch_bounds__(384) void gather_e(const int* __restrict__ userIdx,
                                                const int* __restrict__ itemIdx,
                                                const float* __restrict__ uEmb,
                                                const float* __restrict__ iEmb,
                                                const unsigned short* __restrict__ feat1h,
                                                const unsigned short* __restrict__ feat2h,
                                                unsigned short* __restrict__ E) {
    int b = blockIdx.x;
    int j = threadIdx.x;          // 0..383
    int half = j >= 192;
    int jj = half ? (j - 192) : j;
    int seg = jj >> 6;
    int k = jj & 63;
    unsigned short v;
    if (half == 0) {
        int u = userIdx[b];
        if (seg == 0)      v = f2bf(uEmb[(size_t)u * 64 + k]);
        else if (seg == 1) v = feat1h[(size_t)u * 64 + k];
        else               v = feat2h[(size_t)u * 64 + k];
    } else {
        int it = itemIdx[b];
        if (seg == 0)      v = f2bf(iEmb[(size_t)it * 64 + k]);
        else if (seg == 1) v = feat1h[(size_t)(it + NUM_USERS) * 64 + k];
        else               v = feat2h[(size_t)(it + NUM_USERS) * 64 + k];
    }
    E[(size_t)b * D_CAT + j] = v;
}

// ---------------------------------------------------------------------------
// H1[r][c] = relu( b1[c] + sum_{k<384} E[r][k] * W1[k][c] ), E bf16.
// Round-12 fix: E tile staged in LDS per k-chunk (the wave-uniform GLOBAL
// broadcast loads were the round-7 gemm64 latency trap at 1 block/CU).
// ---------------------------------------------------------------------------
__global__ __launch_bounds__(256) void gemm384_bf16_relu(const unsigned short* __restrict__ E,
                                                         const float* __restrict__ W,
                                                         const float* __restrict__ bia,
                                                         float* __restrict__ H1,
                                                         int n_rows) {
    __shared__ float Wl[128 * 64];   // 32 KB
    __shared__ uint4 El[64 * 16];    // 16 KB: 64 rows x 128 bf16
    int tid = threadIdx.x;
    int lane = tid & 63;
    int wave = tid >> 6;
    int r0 = blockIdx.x * 64;
    int rbase = wave * 16;
    int last = n_rows - 1;

    float acc[16];
    float bv = bia[lane];
#pragma unroll
    for (int i = 0; i < 16; ++i) acc[i] = bv;

    for (int k0 = 0; k0 < D_CAT; k0 += 128) {
        if (k0) __syncthreads();
        for (int i = tid; i < 128 * 64; i += 256) Wl[i] = W[k0 * 64 + i];
        for (int i = tid; i < 64 * 16; i += 256) {
            int row = i >> 4, q = i & 15;
            int r = r0 + row; r = r > last ? last : r;
            El[i] = *(const uint4*)(E + (size_t)r * D_CAT + k0 + q * 8);
        }
        __syncthreads();
#pragma unroll 1
        for (int k = 0; k < 128; k += 8) {
            float w0 = Wl[(k + 0) * 64 + lane];
            float w1 = Wl[(k + 1) * 64 + lane];
            float w2 = Wl[(k + 2) * 64 + lane];
            float w3 = Wl[(k + 3) * 64 + lane];
            float w4 = Wl[(k + 4) * 64 + lane];
            float w5 = Wl[(k + 5) * 64 + lane];
            float w6 = Wl[(k + 6) * 64 + lane];
            float w7 = Wl[(k + 7) * 64 + lane];
#pragma unroll
            for (int i = 0; i < 16; ++i) {
                uint4 q = El[(rbase + i) * 16 + (k >> 3)];   // LDS broadcast
                acc[i] = fmaf(bflo(q.x), w0, acc[i]);
                acc[i] = fmaf(bfhi(q.x), w1, acc[i]);
                acc[i] = fmaf(bflo(q.y), w2, acc[i]);
                acc[i] = fmaf(bfhi(q.y), w3, acc[i]);
                acc[i] = fmaf(bflo(q.z), w4, acc[i]);
                acc[i] = fmaf(bfhi(q.z), w5, acc[i]);
                acc[i] = fmaf(bflo(q.w), w6, acc[i]);
                acc[i] = fmaf(bfhi(q.w), w7, acc[i]);
            }
        }
    }
#pragma unroll
    for (int i = 0; i < 16; ++i) {
        int r = r0 + rbase + i;
        if (r < n_rows) H1[(size_t)r * 64 + lane] = fmaxf(acc[i], 0.f);
    }
}

// ---------------------------------------------------------------------------
// Fused last two layers: z = H1@W2 + b2 (no relu); out = z@W3 + b3
// ---------------------------------------------------------------------------
__global__ __launch_bounds__(256) void mlp23(const float* __restrict__ H1,
                                             const float* __restrict__ W2,
                                             const float* __restrict__ b2,
                                             const float* __restrict__ W3,
                                             const float* __restrict__ b3,
                                             float* __restrict__ out) {
    __shared__ float Wl[64 * 32];
    __shared__ float w3l[32];
    __shared__ float b2l[32];
    int tid = threadIdx.x;
    for (int i = tid; i < 64 * 32; i += 256) Wl[i] = W2[i];
    if (tid < 32) { w3l[tid] = W3[tid]; b2l[tid] = b2[tid]; }
    __syncthreads();

    int lane = tid & 63;
    int wave = tid >> 6;
    int half = lane >> 5;
    int k = lane & 31;
    int gpair = blockIdx.x * 4 + wave;
    int npairs = gridDim.x * 4;
    float b3v = b3[0];
    for (int p = gpair; p * 2 < BATCH; p += npairs) {
        int r = p * 2 + half;
        float acc = b2l[k];
#pragma unroll
        for (int j = 0; j < 64; ++j)
            acc += H1[(size_t)r * 64 + j] * Wl[j * 32 + k];
        acc = acc * w3l[k];
#pragma unroll
        for (int off = 16; off; off >>= 1)
            acc += __shfl_xor(acc, off, 64);
        if (k == 0) out[r] = acc + b3v;
    }
}

// ---------------------------------------------------------------------------
extern "C" void kernel_launch(void* const* d_in, const int* in_sizes, int n_in,
                              void* d_out, int out_size, void* d_ws, size_t ws_size,
                              hipStream_t stream) {
    const int*   userIdx = (const int*)  d_in[0];
    const int*   itemIdx = (const int*)  d_in[1];
    const int*   lap_rows= (const int*)  d_in[2];
    const int*   lap_cols= (const int*)  d_in[3];
    const float* lap_vals= (const float*)d_in[4];
    const float* uEmb    = (const float*)d_in[5];
    const float* iEmb    = (const float*)d_in[6];
    const float* gW0     = (const float*)d_in[7];
    const float* gb0     = (const float*)d_in[8];
    const float* gW1     = (const float*)d_in[9];
    const float* gb1     = (const float*)d_in[10];
    const float* W1      = (const float*)d_in[11];
    const float* b1      = (const float*)d_in[12];
    const float* W2      = (const float*)d_in[13];
    const float* b2      = (const float*)d_in[14];
    const float* W3      = (const float*)d_in[15];
    const float* b3      = (const float*)d_in[16];
    float* out = (float*)d_out;

    const size_t NF = (size_t)N_NODES * EMB;              // 9.6M elements
    char* w = (char*)d_ws;
    unsigned short* bufA = (unsigned short*)w;            // feat1h (19.2 MB)
    unsigned short* bufB = bufA + NF;                     // feat2h (19.2 MB)
    char*  region3 = (char*)(bufB + NF);                  // 38.4 MB multi-use
    // region3 first half: pv during CSR build, then Zh, then E/H1
    int2*  pv      = (int2*)region3;                      // 19.2 MB (dead after fine_scatter)
    unsigned short* Zh = (unsigned short*)region3;        // Z table (19.2 MB)
    unsigned short* E  = (unsigned short*)region3;        // [BATCH,384] bf16 (12.6 MB)
    float* H1 = (float*)(E + (size_t)BATCH * D_CAT);      // [BATCH,64] fp32
    // region3 second half: packed lives through both spmm calls
    int2*  packed  = (int2*)(region3 + NF * sizeof(float)); // 19.2 MB
    int*   row_ptr = (int*)(packed + NNZ);                // N_NODES+1
    int*   boffs   = row_ptr + (N_NODES + 1);             // NBUCK+1 (immutable)
    int*   gtails  = boffs + (NBUCK + 1);                 // NBUCK (mutable tails)
    int*   bcnt    = gtails + NBUCK;                      // NBUCK

    const int ms_grid   = (NNZ + EPB - 1) / EPB;          // 293
    const int spmm_grid = (N_NODES + 3) / 4;              // 37500
    const int gemm_grid = (N_NODES + 63) / 64;            // 2344

    // ---- Build bucketed CSR (shared by both layers)
    hipMemsetAsync(bcnt, 0, NBUCK * sizeof(int), stream);
    bucket_hist<<<128, 1024, 0, stream>>>(lap_rows, bcnt, NNZ);
    bucket_scan<<<1, 1024, 0, stream>>>(bcnt, boffs, gtails, NNZ);
    coarse_multisplit<<<ms_grid, 1024, 0, stream>>>(lap_rows, lap_cols, lap_vals,
                                                    gtails, pv, NNZ);
    fine_scatter<<<NBUCK, 1024, 0, stream>>>(boffs, pv, packed, row_ptr, NNZ);

    // ---- Layer 1: Z = concat(uEmb,iEmb)@gW0 (fp32 read, fused cvt);
    //      feat1 = relu((L+I)Z + gb0)
    gemm_table_f32<<<gemm_grid, 256, 0, stream>>>(uEmb, iEmb, gW0, Zh, N_NODES);
    spmm_bias_relu<<<spmm_grid, 256, 0, stream>>>(row_ptr, packed, (const unsigned*)Zh,
                                                  gb0, (unsigned*)bufA, N_NODES);

    // ---- Layer 2: Z = feat1@gW1 ; feat2 = relu((L+I)Z + gb1)
    gemm_table_bf16<<<gemm_grid, 256, 0, stream>>>((const unsigned*)bufA, gW1, Zh, N_NODES);
    spmm_bias_relu<<<spmm_grid, 256, 0, stream>>>(row_ptr, packed, (const unsigned*)Zh,
                                                  gb1, (unsigned*)bufB, N_NODES);

    // ---- Gather per-sample concatenated features (E overlays Zh; Zh dead)
    gather_e<<<BATCH, 384, 0, stream>>>(userIdx, itemIdx, uEmb, iEmb, bufA, bufB, E);

    // ---- MLP
    gemm384_bf16_relu<<<(BATCH + 63) / 64, 256, 0, stream>>>(E, W1, b1, H1, BATCH);
    mlp23<<<512, 256, 0, stream>>>(H1, W2, b2, W3, b3, out);
}

// Round 13
// 517.385 us; speedup vs baseline: 4.6469x; 1.0045x over previous
//
#include <hip/hip_runtime.h>
#include <hip/hip_bf16.h>

// Problem constants (from reference)
#define NUM_USERS 100000
#define NUM_ITEMS 50000
#define N_NODES   150000   // NUM_USERS + NUM_ITEMS
#define EMB       64
#define NNZ       2400000
#define BATCH     16384
#define D_CAT     384      // EMB*3*2
#define BSHIFT    8        // 256 rows per bucket: multisplit segment ~2 lines
#define NBUCK     ((N_NODES + 255) >> 8)   // 586
#define EPB       8192     // edges per multisplit block

// ---- bf16 helpers (bit-level, RN-even for f32->bf16) -----------------------
__device__ __forceinline__ unsigned short f2bf(float f) {
    unsigned u = __float_as_uint(f);
    unsigned r = u + 0x7fffu + ((u >> 16) & 1u);
    return (unsigned short)(r >> 16);
}
__device__ __forceinline__ float bflo(unsigned u) { return __uint_as_float(u << 16); }
__device__ __forceinline__ float bfhi(unsigned u) { return __uint_as_float(u & 0xffff0000u); }

// ---------------------------------------------------------------------------
// Bucket histogram, LDS-aggregated (one global atomic per non-empty bucket
// per block; round-8 lesson: device atomics are memory-side ~32 B each).
// ---------------------------------------------------------------------------
__global__ __launch_bounds__(1024) void bucket_hist(const int* __restrict__ rows,
                                                    int* __restrict__ bcnt, int nnz) {
    __shared__ int h[NBUCK];
    int tid = threadIdx.x;
    for (int i = tid; i < NBUCK; i += 1024) h[i] = 0;
    __syncthreads();
    for (int i = blockIdx.x * 1024 + tid; i < nnz; i += gridDim.x * 1024)
        atomicAdd(&h[rows[i] >> BSHIFT], 1);
    __syncthreads();
    for (int i = tid; i < NBUCK; i += 1024) {
        int c = h[i];
        if (c) atomicAdd(&bcnt[i], c);
    }
}

// ---------------------------------------------------------------------------
// Exclusive scan over the 586 bucket counts (single block, 1 elem/thread).
// Emits boffs (+sentinel) and gtails (mutable copy for the multisplit).
// ---------------------------------------------------------------------------
__global__ __launch_bounds__(1024) void bucket_scan(const int* __restrict__ bcnt,
                                                    int* __restrict__ boffs,
                                                    int* __restrict__ gtails, int nnz) {
    __shared__ int s[1024];
    int t = threadIdx.x;
    int x = (t < NBUCK) ? bcnt[t] : 0;
    s[t] = x;
    __syncthreads();
#pragma unroll
    for (int off = 1; off < 1024; off <<= 1) {
        int v = (t >= off) ? s[t - off] : 0;
        __syncthreads();
        s[t] += v;
        __syncthreads();
    }
    if (t < NBUCK) {
        int e = s[t] - x;
        boffs[t] = e;
        gtails[t] = e;
    }
    if (t == 0) boffs[NBUCK] = nnz;
}

// ---------------------------------------------------------------------------
// LDS-staged multisplit into 256-row buckets (~14-edge per-block segments ≈
// 2 cache lines -> near-single-CU line ownership).
// pv payload: .x = (r_local<<18) | col  (rl<256, col<2^18), .y = val
// ---------------------------------------------------------------------------
__global__ __launch_bounds__(1024) void coarse_multisplit(const int* __restrict__ rows,
                                                          const int* __restrict__ cols,
                                                          const float* __restrict__ vals,
                                                          int* __restrict__ gtails,
                                                          int2* __restrict__ pv, int nnz) {
    __shared__ int hcnt[NBUCK];
    int tid = threadIdx.x;
    int e0 = blockIdx.x * EPB;
    int e1 = e0 + EPB < nnz ? e0 + EPB : nnz;

    for (int i = tid; i < NBUCK; i += 1024) hcnt[i] = 0;
    __syncthreads();
    for (int i = e0 + tid; i < e1; i += 1024)
        atomicAdd(&hcnt[rows[i] >> BSHIFT], 1);
    __syncthreads();
    for (int i = tid; i < NBUCK; i += 1024) {
        int c = hcnt[i];
        if (c) hcnt[i] = atomicAdd(&gtails[i], c);   // global base for this block
    }
    __syncthreads();
    for (int i = e0 + tid; i < e1; i += 1024) {
        int r = rows[i];
        int pos = atomicAdd(&hcnt[r >> BSHIFT], 1);  // LDS bump from global base
        pv[pos] = make_int2(((r & 255) << 18) | cols[i], __float_as_int(vals[i]));
    }
}

// ---------------------------------------------------------------------------
// Fine scatter within a 256-row bucket + row_ptr production (int LDS atomics,
// proven pattern).
// ---------------------------------------------------------------------------
__global__ __launch_bounds__(1024) void fine_scatter(const int* __restrict__ boffs,
                                                     const int2* __restrict__ pv,
                                                     int2* __restrict__ packed,
                                                     int* __restrict__ row_ptr, int nnz) {
    __shared__ int rcnt[256];
    __shared__ int loff[256];
    int b = blockIdx.x;
    int tid = threadIdx.x;
    int lo = boffs[b], hi = boffs[b + 1];
    int r0 = b << BSHIFT;
    int nr = N_NODES - r0; if (nr > 256) nr = 256;

    if (tid < 256) rcnt[tid] = 0;
    __syncthreads();
    for (int i = lo + tid; i < hi; i += 1024)
        atomicAdd(&rcnt[pv[i].x >> 18], 1);
    __syncthreads();
    if (tid < 256) loff[tid] = rcnt[tid];
    __syncthreads();
#pragma unroll
    for (int off = 1; off < 256; off <<= 1) {
        int v = (tid < 256 && tid >= off) ? loff[tid - off] : 0;
        __syncthreads();
        if (tid < 256) loff[tid] += v;
        __syncthreads();
    }
    if (tid < 256) {
        int e = lo + loff[tid] - rcnt[tid];    // exclusive prefix + bucket base
        loff[tid] = e;
        if (tid < nr) row_ptr[r0 + tid] = e;
    }
    if (b == 0 && tid == 0) row_ptr[N_NODES] = nnz;
    __syncthreads();
    for (int i = lo + tid; i < hi; i += 1024) {
        int2 e = pv[i];
        int rl = e.x >> 18;
        int pos = atomicAdd(&loff[rl], 1);
        packed[pos] = make_int2(e.x & 0x3FFFF, e.y);
    }
}

// ---------------------------------------------------------------------------
// Layer-1 table GEMM directly from fp32 embeddings (fused cvt):
// Z = concat(uEmb,iEmb) @ W, output bf16. X tile staged in LDS as fp32.
// ---------------------------------------------------------------------------
__global__ __launch_bounds__(256) void gemm_table_f32(const float* __restrict__ uE,
                                                      const float* __restrict__ iE,
                                                      const float* __restrict__ W,
                                                      unsigned short* __restrict__ Zh,
                                                      int n_rows) {
    __shared__ float Wl[64 * 64];        // 16 KB
    __shared__ float Xf[64 * 64];        // 16 KB
    int tid = threadIdx.x;
    int lane = tid & 63;
    int wave = tid >> 6;
    int r0 = blockIdx.x * 64;
    int last = n_rows - 1;

    for (int i = tid; i < 64 * 64; i += 256) Wl[i] = W[i];
    for (int i = tid; i < 64 * 16; i += 256) {       // 1024 float4
        int row = i >> 4, q = i & 15;
        int r = r0 + row; r = r > last ? last : r;
        const float4* src = (r < NUM_USERS)
            ? (const float4*)(uE + (size_t)r * 64)
            : (const float4*)(iE + (size_t)(r - NUM_USERS) * 64);
        ((float4*)Xf)[i] = src[q];
    }
    __syncthreads();

    int rbase = wave * 16;
    float acc[16];
#pragma unroll
    for (int i = 0; i < 16; ++i) acc[i] = 0.f;

#pragma unroll 1
    for (int kc = 0; kc < 16; ++kc) {    // 4 k-values per chunk
        float w0 = Wl[(kc * 4 + 0) * 64 + lane];
        float w1 = Wl[(kc * 4 + 1) * 64 + lane];
        float w2 = Wl[(kc * 4 + 2) * 64 + lane];
        float w3 = Wl[(kc * 4 + 3) * 64 + lane];
#pragma unroll
        for (int i = 0; i < 16; ++i) {
            float4 q = ((const float4*)Xf)[(rbase + i) * 16 + kc];  // LDS broadcast
            acc[i] = fmaf(q.x, w0, acc[i]);
            acc[i] = fmaf(q.y, w1, acc[i]);
            acc[i] = fmaf(q.z, w2, acc[i]);
            acc[i] = fmaf(q.w, w3, acc[i]);
        }
    }
#pragma unroll
    for (int i = 0; i < 16; ++i) {
        int r = r0 + rbase + i;
        if (r < n_rows) Zh[(size_t)r * 64 + lane] = f2bf(acc[i]);
    }
}

// ---------------------------------------------------------------------------
// Layer-2 table GEMM from the bf16 feature table.
// ---------------------------------------------------------------------------
__global__ __launch_bounds__(256) void gemm_table_bf16(const unsigned* __restrict__ Xh,
                                                       const float* __restrict__ W,
                                                       unsigned short* __restrict__ Zh,
                                                       int n_rows) {
    __shared__ float Wl[64 * 64];        // 16 KB
    __shared__ uint4 Xl4[64 * 8];        // 8 KB: 64 rows x 32 uints (bf16x2)
    int tid = threadIdx.x;
    int lane = tid & 63;
    int wave = tid >> 6;
    int r0 = blockIdx.x * 64;
    int nr = n_rows - r0; if (nr > 64) nr = 64;

    for (int i = tid; i < 64 * 64; i += 256) Wl[i] = W[i];
    const uint4* Xg4 = (const uint4*)(Xh + (size_t)r0 * 32);
    for (int i = tid; i < nr * 8; i += 256) Xl4[i] = Xg4[i];
    __syncthreads();

    const unsigned* Xl = (const unsigned*)Xl4;
    int rbase = wave * 16;
    float acc[16];
#pragma unroll
    for (int i = 0; i < 16; ++i) acc[i] = 0.f;

#pragma unroll 1
    for (int kc = 0; kc < 8; ++kc) {     // 8 k-values per chunk
        float w0 = Wl[(kc * 8 + 0) * 64 + lane];
        float w1 = Wl[(kc * 8 + 1) * 64 + lane];
        float w2 = Wl[(kc * 8 + 2) * 64 + lane];
        float w3 = Wl[(kc * 8 + 3) * 64 + lane];
        float w4 = Wl[(kc * 8 + 4) * 64 + lane];
        float w5 = Wl[(kc * 8 + 5) * 64 + lane];
        float w6 = Wl[(kc * 8 + 6) * 64 + lane];
        float w7 = Wl[(kc * 8 + 7) * 64 + lane];
#pragma unroll
        for (int i = 0; i < 16; ++i) {
            uint4 q = *(const uint4*)&Xl[(rbase + i) * 32 + kc * 4];  // broadcast
            acc[i] = fmaf(bflo(q.x), w0, acc[i]);
            acc[i] = fmaf(bfhi(q.x), w1, acc[i]);
            acc[i] = fmaf(bflo(q.y), w2, acc[i]);
            acc[i] = fmaf(bfhi(q.y), w3, acc[i]);
            acc[i] = fmaf(bflo(q.z), w4, acc[i]);
            acc[i] = fmaf(bfhi(q.z), w5, acc[i]);
            acc[i] = fmaf(bflo(q.w), w6, acc[i]);
            acc[i] = fmaf(bfhi(q.w), w7, acc[i]);
        }
    }
#pragma unroll
    for (int i = 0; i < 16; ++i) {
        int r = r0 + rbase + i;
        if (r < n_rows) Zh[(size_t)r * 64 + lane] = f2bf(acc[i]);
    }
}

// ---------------------------------------------------------------------------
// SPMM + bias + relu: out[r] = relu( Z[r] + sum_edges v * Z[c] + bias ), bf16.
// Round-13: quarter-wave per edge (16 lanes x uint2 = bf16x4/lane) -> one
// gather instruction covers 4 edges; 4-deep unroll = 16 edges in flight/wave
// (round-12 half-wave had 8). Kernel was latency-bound: VALUBusy 36%,
// FETCH L3-served. Register accumulation (LDS-acc variant was 12x slower).
// Edge coverage: quarter q visits e ≡ (row_ptr[r]+q) mod 4 — exact partition.
// ---------------------------------------------------------------------------
__global__ __launch_bounds__(256) void spmm_bias_relu(const int* __restrict__ row_ptr,
                                                      const int2* __restrict__ packed,
                                                      const uint2* __restrict__ zh2,   // bf16x4, 16/row
                                                      const float* __restrict__ bias,  // [64] fp32
                                                      uint2* __restrict__ outh2,       // bf16x4, 16/row
                                                      int n_rows) {
    int tid = threadIdx.x;
    int lane = tid & 63;
    int wave = tid >> 6;
    int q = lane >> 4;                 // 0..3 quarter
    int k = lane & 15;                 // column group (4 cols per lane)
    int r = blockIdx.x * 4 + wave;
    if (r >= n_rows) return;

    uint2 su = zh2[(size_t)r * 16 + k];
    float4 acc;
    acc.x = q ? 0.f : bflo(su.x);
    acc.y = q ? 0.f : bfhi(su.x);
    acc.z = q ? 0.f : bflo(su.y);
    acc.w = q ? 0.f : bfhi(su.y);

    int e = row_ptr[r] + q;
    int end = row_ptr[r + 1];
    for (; e + 13 < end; e += 16) {    // 16 edges/iter (4 per quarter)
        int2 p0 = packed[e + 0];
        int2 p1 = packed[e + 4];
        int2 p2 = packed[e + 8];
        int2 p3 = packed[e + 12];
        uint2 z0 = zh2[(size_t)p0.x * 16 + k];
        uint2 z1 = zh2[(size_t)p1.x * 16 + k];
        uint2 z2 = zh2[(size_t)p2.x * 16 + k];
        uint2 z3 = zh2[(size_t)p3.x * 16 + k];
        float v0 = __int_as_float(p0.y), v1 = __int_as_float(p1.y);
        float v2 = __int_as_float(p2.y), v3 = __int_as_float(p3.y);
        acc.x = fmaf(v0, bflo(z0.x), acc.x); acc.y = fmaf(v0, bfhi(z0.x), acc.y);
        acc.z = fmaf(v0, bflo(z0.y), acc.z); acc.w = fmaf(v0, bfhi(z0.y), acc.w);
        acc.x = fmaf(v1, bflo(z1.x), acc.x); acc.y = fmaf(v1, bfhi(z1.x), acc.y);
        acc.z = fmaf(v1, bflo(z1.y), acc.z); acc.w = fmaf(v1, bfhi(z1.y), acc.w);
        acc.x = fmaf(v2, bflo(z2.x), acc.x); acc.y = fmaf(v2, bfhi(z2.x), acc.y);
        acc.z = fmaf(v2, bflo(z2.y), acc.z); acc.w = fmaf(v2, bfhi(z2.y), acc.w);
        acc.x = fmaf(v3, bflo(z3.x), acc.x); acc.y = fmaf(v3, bfhi(z3.x), acc.y);
        acc.z = fmaf(v3, bflo(z3.y), acc.z); acc.w = fmaf(v3, bfhi(z3.y), acc.w);
    }
    for (; e < end; e += 4) {
        int2 p = packed[e];
        uint2 z = zh2[(size_t)p.x * 16 + k];
        float v = __int_as_float(p.y);
        acc.x = fmaf(v, bflo(z.x), acc.x); acc.y = fmaf(v, bfhi(z.x), acc.y);
        acc.z = fmaf(v, bflo(z.y), acc.z); acc.w = fmaf(v, bfhi(z.y), acc.w);
    }

    // combine the 4 quarters
    acc.x += __shfl_xor(acc.x, 16, 64);
    acc.y += __shfl_xor(acc.y, 16, 64);
    acc.z += __shfl_xor(acc.z, 16, 64);
    acc.w += __shfl_xor(acc.w, 16, 64);
    acc.x += __shfl_xor(acc.x, 32, 64);
    acc.y += __shfl_xor(acc.y, 32, 64);
    acc.z += __shfl_xor(acc.z, 32, 64);
    acc.w += __shfl_xor(acc.w, 32, 64);
    if (q == 0) {
        float4 bv = ((const float4*)bias)[k];
        float a = fmaxf(acc.x + bv.x, 0.f);
        float b = fmaxf(acc.y + bv.y, 0.f);
        float c = fmaxf(acc.z + bv.z, 0.f);
        float d = fmaxf(acc.w + bv.w, 0.f);
        outh2[(size_t)r * 16 + k] = make_uint2(
            ((unsigned)f2bf(b) << 16) | (unsigned)f2bf(a),
            ((unsigned)f2bf(d) << 16) | (unsigned)f2bf(c));
    }
}

// ---------------------------------------------------------------------------
// Gather concatenated per-sample features -> bf16 E (one 384-thread block/row)
// ---------------------------------------------------------------------------
__global__ __launch_bounds__(384) void gather_e(const int* __restrict__ userIdx,
                                                const int* __restrict__ itemIdx,
                                                const float* __restrict__ uEmb,
                                                const float* __restrict__ iEmb,
                                                const unsigned short* __restrict__ feat1h,
                                                const unsigned short* __restrict__ feat2h,
                                                unsigned short* __restrict__ E) {
    int b = blockIdx.x;
    int j = threadIdx.x;          // 0..383
    int half = j >= 192;
    int jj = half ? (j - 192) : j;
    int seg = jj >> 6;
    int k = jj & 63;
    unsigned short v;
    if (half == 0) {
        int u = userIdx[b];
        if (seg == 0)      v = f2bf(uEmb[(size_t)u * 64 + k]);
        else if (seg == 1) v = feat1h[(size_t)u * 64 + k];
        else               v = feat2h[(size_t)u * 64 + k];
    } else {
        int it = itemIdx[b];
        if (seg == 0)      v = f2bf(iEmb[(size_t)it * 64 + k]);
        else if (seg == 1) v = feat1h[(size_t)(it + NUM_USERS) * 64 + k];
        else               v = feat2h[(size_t)(it + NUM_USERS) * 64 + k];
    }
    E[(size_t)b * D_CAT + j] = v;
}

// ---------------------------------------------------------------------------
// H1[r][c] = relu( b1[c] + sum_{k<384} E[r][k] * W1[k][c] ), E bf16.
// E tile staged in LDS per k-chunk (global wave-uniform broadcast loads were
// the round-7 latency trap).
// ---------------------------------------------------------------------------
__global__ __launch_bounds__(256) void gemm384_bf16_relu(const unsigned short* __restrict__ E,
                                                         const float* __restrict__ W,
                                                         const float* __restrict__ bia,
                                                         float* __restrict__ H1,
                                                         int n_rows) {
    __shared__ float Wl[128 * 64];   // 32 KB
    __shared__ uint4 El[64 * 16];    // 16 KB: 64 rows x 128 bf16
    int tid = threadIdx.x;
    int lane = tid & 63;
    int wave = tid >> 6;
    int r0 = blockIdx.x * 64;
    int rbase = wave * 16;
    int last = n_rows - 1;

    float acc[16];
    float bv = bia[lane];
#pragma unroll
    for (int i = 0; i < 16; ++i) acc[i] = bv;

    for (int k0 = 0; k0 < D_CAT; k0 += 128) {
        if (k0) __syncthreads();
        for (int i = tid; i < 128 * 64; i += 256) Wl[i] = W[k0 * 64 + i];
        for (int i = tid; i < 64 * 16; i += 256) {
            int row = i >> 4, q = i & 15;
            int r = r0 + row; r = r > last ? last : r;
            El[i] = *(const uint4*)(E + (size_t)r * D_CAT + k0 + q * 8);
        }
        __syncthreads();
#pragma unroll 1
        for (int k = 0; k < 128; k += 8) {
            float w0 = Wl[(k + 0) * 64 + lane];
            float w1 = Wl[(k + 1) * 64 + lane];
            float w2 = Wl[(k + 2) * 64 + lane];
            float w3 = Wl[(k + 3) * 64 + lane];
            float w4 = Wl[(k + 4) * 64 + lane];
            float w5 = Wl[(k + 5) * 64 + lane];
            float w6 = Wl[(k + 6) * 64 + lane];
            float w7 = Wl[(k + 7) * 64 + lane];
#pragma unroll
            for (int i = 0; i < 16; ++i) {
                uint4 q = El[(rbase + i) * 16 + (k >> 3)];   // LDS broadcast
                acc[i] = fmaf(bflo(q.x), w0, acc[i]);
                acc[i] = fmaf(bfhi(q.x), w1, acc[i]);
                acc[i] = fmaf(bflo(q.y), w2, acc[i]);
                acc[i] = fmaf(bfhi(q.y), w3, acc[i]);
                acc[i] = fmaf(bflo(q.z), w4, acc[i]);
                acc[i] = fmaf(bfhi(q.z), w5, acc[i]);
                acc[i] = fmaf(bflo(q.w), w6, acc[i]);
                acc[i] = fmaf(bfhi(q.w), w7, acc[i]);
            }
        }
    }
#pragma unroll
    for (int i = 0; i < 16; ++i) {
        int r = r0 + rbase + i;
        if (r < n_rows) H1[(size_t)r * 64 + lane] = fmaxf(acc[i], 0.f);
    }
}

// ---------------------------------------------------------------------------
// Fused last two layers: z = H1@W2 + b2 (no relu); out = z@W3 + b3
// ---------------------------------------------------------------------------
__global__ __launch_bounds__(256) void mlp23(const float* __restrict__ H1,
                                             const float* __restrict__ W2,
                                             const float* __restrict__ b2,
                                             const float* __restrict__ W3,
                                             const float* __restrict__ b3,
                                             float* __restrict__ out) {
    __shared__ float Wl[64 * 32];
    __shared__ float w3l[32];
    __shared__ float b2l[32];
    int tid = threadIdx.x;
    for (int i = tid; i < 64 * 32; i += 256) Wl[i] = W2[i];
    if (tid < 32) { w3l[tid] = W3[tid]; b2l[tid] = b2[tid]; }
    __syncthreads();

    int lane = tid & 63;
    int wave = tid >> 6;
    int half = lane >> 5;
    int k = lane & 31;
    int gpair = blockIdx.x * 4 + wave;
    int npairs = gridDim.x * 4;
    float b3v = b3[0];
    for (int p = gpair; p * 2 < BATCH; p += npairs) {
        int r = p * 2 + half;
        float acc = b2l[k];
#pragma unroll
        for (int j = 0; j < 64; ++j)
            acc += H1[(size_t)r * 64 + j] * Wl[j * 32 + k];
        acc = acc * w3l[k];
#pragma unroll
        for (int off = 16; off; off >>= 1)
            acc += __shfl_xor(acc, off, 64);
        if (k == 0) out[r] = acc + b3v;
    }
}

// ---------------------------------------------------------------------------
extern "C" void kernel_launch(void* const* d_in, const int* in_sizes, int n_in,
                              void* d_out, int out_size, void* d_ws, size_t ws_size,
                              hipStream_t stream) {
    const int*   userIdx = (const int*)  d_in[0];
    const int*   itemIdx = (const int*)  d_in[1];
    const int*   lap_rows= (const int*)  d_in[2];
    const int*   lap_cols= (const int*)  d_in[3];
    const float* lap_vals= (const float*)d_in[4];
    const float* uEmb    = (const float*)d_in[5];
    const float* iEmb    = (const float*)d_in[6];
    const float* gW0     = (const float*)d_in[7];
    const float* gb0     = (const float*)d_in[8];
    const float* gW1     = (const float*)d_in[9];
    const float* gb1     = (const float*)d_in[10];
    const float* W1      = (const float*)d_in[11];
    const float* b1      = (const float*)d_in[12];
    const float* W2      = (const float*)d_in[13];
    const float* b2      = (const float*)d_in[14];
    const float* W3      = (const float*)d_in[15];
    const float* b3      = (const float*)d_in[16];
    float* out = (float*)d_out;

    const size_t NF = (size_t)N_NODES * EMB;              // 9.6M elements
    char* w = (char*)d_ws;
    unsigned short* bufA = (unsigned short*)w;            // feat1h (19.2 MB)
    unsigned short* bufB = bufA + NF;                     // feat2h (19.2 MB)
    char*  region3 = (char*)(bufB + NF);                  // 38.4 MB multi-use
    // region3 first half: pv during CSR build, then Zh, then E/H1
    int2*  pv      = (int2*)region3;                      // 19.2 MB (dead after fine_scatter)
    unsigned short* Zh = (unsigned short*)region3;        // Z table (19.2 MB)
    unsigned short* E  = (unsigned short*)region3;        // [BATCH,384] bf16 (12.6 MB)
    float* H1 = (float*)(E + (size_t)BATCH * D_CAT);      // [BATCH,64] fp32
    // region3 second half: packed lives through both spmm calls
    int2*  packed  = (int2*)(region3 + NF * sizeof(float)); // 19.2 MB
    int*   row_ptr = (int*)(packed + NNZ);                // N_NODES+1
    int*   boffs   = row_ptr + (N_NODES + 1);             // NBUCK+1 (immutable)
    int*   gtails  = boffs + (NBUCK + 1);                 // NBUCK (mutable tails)
    int*   bcnt    = gtails + NBUCK;                      // NBUCK

    const int ms_grid   = (NNZ + EPB - 1) / EPB;          // 293
    const int spmm_grid = (N_NODES + 3) / 4;              // 37500
    const int gemm_grid = (N_NODES + 63) / 64;            // 2344

    // ---- Build bucketed CSR (shared by both layers)
    hipMemsetAsync(bcnt, 0, NBUCK * sizeof(int), stream);
    bucket_hist<<<128, 1024, 0, stream>>>(lap_rows, bcnt, NNZ);
    bucket_scan<<<1, 1024, 0, stream>>>(bcnt, boffs, gtails, NNZ);
    coarse_multisplit<<<ms_grid, 1024, 0, stream>>>(lap_rows, lap_cols, lap_vals,
                                                    gtails, pv, NNZ);
    fine_scatter<<<NBUCK, 1024, 0, stream>>>(boffs, pv, packed, row_ptr, NNZ);

    // ---- Layer 1: Z = concat(uEmb,iEmb)@gW0 ; feat1 = relu((L+I)Z + gb0)
    gemm_table_f32<<<gemm_grid, 256, 0, stream>>>(uEmb, iEmb, gW0, Zh, N_NODES);
    spmm_bias_relu<<<spmm_grid, 256, 0, stream>>>(row_ptr, packed, (const uint2*)Zh,
                                                  gb0, (uint2*)bufA, N_NODES);

    // ---- Layer 2: Z = feat1@gW1 ; feat2 = relu((L+I)Z + gb1)
    gemm_table_bf16<<<gemm_grid, 256, 0, stream>>>((const unsigned*)bufA, gW1, Zh, N_NODES);
    spmm_bias_relu<<<spmm_grid, 256, 0, stream>>>(row_ptr, packed, (const uint2*)Zh,
                                                  gb1, (uint2*)bufB, N_NODES);

    // ---- Gather per-sample concatenated features (E overlays Zh; Zh dead)
    gather_e<<<BATCH, 384, 0, stream>>>(userIdx, itemIdx, uEmb, iEmb, bufA, bufB, E);

    // ---- MLP
    gemm384_bf16_relu<<<(BATCH + 63) / 64, 256, 0, stream>>>(E, W1, b1, H1, BATCH);
    mlp23<<<512, 256, 0, stream>>>(H1, W2, b2, W3, b3, out);
}

// Round 14
// 492.523 us; speedup vs baseline: 4.8815x; 1.0505x over previous
//
#include <hip/hip_runtime.h>
#include <hip/hip_bf16.h>

// Problem constants (from reference)
#define NUM_USERS 100000
#define NUM_ITEMS 50000
#define N_NODES   150000   // NUM_USERS + NUM_ITEMS
#define EMB       64
#define NNZ       2400000
#define BATCH     16384
#define D_CAT     384      // EMB*3*2
#define BSHIFT    8        // 256 rows per bucket: multisplit segment ~2 lines
#define NBUCK     ((N_NODES + 255) >> 8)   // 586
#define EPB       8192     // edges per multisplit block

// ---- bf16 helpers (bit-level, RN-even for f32->bf16) -----------------------
__device__ __forceinline__ unsigned short f2bf(float f) {
    unsigned u = __float_as_uint(f);
    unsigned r = u + 0x7fffu + ((u >> 16) & 1u);
    return (unsigned short)(r >> 16);
}
__device__ __forceinline__ float bflo(unsigned u) { return __uint_as_float(u << 16); }
__device__ __forceinline__ float bfhi(unsigned u) { return __uint_as_float(u & 0xffff0000u); }

// ---------------------------------------------------------------------------
// Bucket histogram, LDS-aggregated (one global atomic per non-empty bucket
// per block; round-8 lesson: device atomics are memory-side ~32 B each).
// ---------------------------------------------------------------------------
__global__ __launch_bounds__(1024) void bucket_hist(const int* __restrict__ rows,
                                                    int* __restrict__ bcnt, int nnz) {
    __shared__ int h[NBUCK];
    int tid = threadIdx.x;
    for (int i = tid; i < NBUCK; i += 1024) h[i] = 0;
    __syncthreads();
    for (int i = blockIdx.x * 1024 + tid; i < nnz; i += gridDim.x * 1024)
        atomicAdd(&h[rows[i] >> BSHIFT], 1);
    __syncthreads();
    for (int i = tid; i < NBUCK; i += 1024) {
        int c = h[i];
        if (c) atomicAdd(&bcnt[i], c);
    }
}

// ---------------------------------------------------------------------------
// Exclusive scan over the 586 bucket counts (single block, 1 elem/thread).
// ---------------------------------------------------------------------------
__global__ __launch_bounds__(1024) void bucket_scan(const int* __restrict__ bcnt,
                                                    int* __restrict__ boffs,
                                                    int* __restrict__ gtails, int nnz) {
    __shared__ int s[1024];
    int t = threadIdx.x;
    int x = (t < NBUCK) ? bcnt[t] : 0;
    s[t] = x;
    __syncthreads();
#pragma unroll
    for (int off = 1; off < 1024; off <<= 1) {
        int v = (t >= off) ? s[t - off] : 0;
        __syncthreads();
        s[t] += v;
        __syncthreads();
    }
    if (t < NBUCK) {
        int e = s[t] - x;
        boffs[t] = e;
        gtails[t] = e;
    }
    if (t == 0) boffs[NBUCK] = nnz;
}

// ---------------------------------------------------------------------------
// LDS-staged multisplit into 256-row buckets (~14-edge per-block segments ≈
// 2 cache lines -> near-single-CU line ownership).
// pv payload: .x = (r_local<<18) | col  (rl<256, col<2^18), .y = val
// ---------------------------------------------------------------------------
__global__ __launch_bounds__(1024) void coarse_multisplit(const int* __restrict__ rows,
                                                          const int* __restrict__ cols,
                                                          const float* __restrict__ vals,
                                                          int* __restrict__ gtails,
                                                          int2* __restrict__ pv, int nnz) {
    __shared__ int hcnt[NBUCK];
    int tid = threadIdx.x;
    int e0 = blockIdx.x * EPB;
    int e1 = e0 + EPB < nnz ? e0 + EPB : nnz;

    for (int i = tid; i < NBUCK; i += 1024) hcnt[i] = 0;
    __syncthreads();
    for (int i = e0 + tid; i < e1; i += 1024)
        atomicAdd(&hcnt[rows[i] >> BSHIFT], 1);
    __syncthreads();
    for (int i = tid; i < NBUCK; i += 1024) {
        int c = hcnt[i];
        if (c) hcnt[i] = atomicAdd(&gtails[i], c);   // global base for this block
    }
    __syncthreads();
    for (int i = e0 + tid; i < e1; i += 1024) {
        int r = rows[i];
        int pos = atomicAdd(&hcnt[r >> BSHIFT], 1);  // LDS bump from global base
        pv[pos] = make_int2(((r & 255) << 18) | cols[i], __float_as_int(vals[i]));
    }
}

// ---------------------------------------------------------------------------
// Fine scatter within a 256-row bucket + row_ptr production (int LDS atomics,
// proven pattern).
// ---------------------------------------------------------------------------
__global__ __launch_bounds__(1024) void fine_scatter(const int* __restrict__ boffs,
                                                     const int2* __restrict__ pv,
                                                     int2* __restrict__ packed,
                                                     int* __restrict__ row_ptr, int nnz) {
    __shared__ int rcnt[256];
    __shared__ int loff[256];
    int b = blockIdx.x;
    int tid = threadIdx.x;
    int lo = boffs[b], hi = boffs[b + 1];
    int r0 = b << BSHIFT;
    int nr = N_NODES - r0; if (nr > 256) nr = 256;

    if (tid < 256) rcnt[tid] = 0;
    __syncthreads();
    for (int i = lo + tid; i < hi; i += 1024)
        atomicAdd(&rcnt[pv[i].x >> 18], 1);
    __syncthreads();
    if (tid < 256) loff[tid] = rcnt[tid];
    __syncthreads();
#pragma unroll
    for (int off = 1; off < 256; off <<= 1) {
        int v = (tid < 256 && tid >= off) ? loff[tid - off] : 0;
        __syncthreads();
        if (tid < 256) loff[tid] += v;
        __syncthreads();
    }
    if (tid < 256) {
        int e = lo + loff[tid] - rcnt[tid];    // exclusive prefix + bucket base
        loff[tid] = e;
        if (tid < nr) row_ptr[r0 + tid] = e;
    }
    if (b == 0 && tid == 0) row_ptr[N_NODES] = nnz;
    __syncthreads();
    for (int i = lo + tid; i < hi; i += 1024) {
        int2 e = pv[i];
        int rl = e.x >> 18;
        int pos = atomicAdd(&loff[rl], 1);
        packed[pos] = make_int2(e.x & 0x3FFFF, e.y);
    }
}

// ---------------------------------------------------------------------------
// Layer-1 table GEMM directly from fp32 embeddings (fused cvt):
// Z = concat(uEmb,iEmb) @ W, output bf16. X tile staged in LDS as fp32.
// ---------------------------------------------------------------------------
__global__ __launch_bounds__(256) void gemm_table_f32(const float* __restrict__ uE,
                                                      const float* __restrict__ iE,
                                                      const float* __restrict__ W,
                                                      unsigned short* __restrict__ Zh,
                                                      int n_rows) {
    __shared__ float Wl[64 * 64];        // 16 KB
    __shared__ float Xf[64 * 64];        // 16 KB
    int tid = threadIdx.x;
    int lane = tid & 63;
    int wave = tid >> 6;
    int r0 = blockIdx.x * 64;
    int last = n_rows - 1;

    for (int i = tid; i < 64 * 64; i += 256) Wl[i] = W[i];
    for (int i = tid; i < 64 * 16; i += 256) {       // 1024 float4
        int row = i >> 4, q = i & 15;
        int r = r0 + row; r = r > last ? last : r;
        const float4* src = (r < NUM_USERS)
            ? (const float4*)(uE + (size_t)r * 64)
            : (const float4*)(iE + (size_t)(r - NUM_USERS) * 64);
        ((float4*)Xf)[i] = src[q];
    }
    __syncthreads();

    int rbase = wave * 16;
    float acc[16];
#pragma unroll
    for (int i = 0; i < 16; ++i) acc[i] = 0.f;

#pragma unroll 1
    for (int kc = 0; kc < 16; ++kc) {    // 4 k-values per chunk
        float w0 = Wl[(kc * 4 + 0) * 64 + lane];
        float w1 = Wl[(kc * 4 + 1) * 64 + lane];
        float w2 = Wl[(kc * 4 + 2) * 64 + lane];
        float w3 = Wl[(kc * 4 + 3) * 64 + lane];
#pragma unroll
        for (int i = 0; i < 16; ++i) {
            float4 q = ((const float4*)Xf)[(rbase + i) * 16 + kc];  // LDS broadcast
            acc[i] = fmaf(q.x, w0, acc[i]);
            acc[i] = fmaf(q.y, w1, acc[i]);
            acc[i] = fmaf(q.z, w2, acc[i]);
            acc[i] = fmaf(q.w, w3, acc[i]);
        }
    }
#pragma unroll
    for (int i = 0; i < 16; ++i) {
        int r = r0 + rbase + i;
        if (r < n_rows) Zh[(size_t)r * 64 + lane] = f2bf(acc[i]);
    }
}

// ---------------------------------------------------------------------------
// Layer-2 table GEMM from the bf16 feature table.
// ---------------------------------------------------------------------------
__global__ __launch_bounds__(256) void gemm_table_bf16(const unsigned* __restrict__ Xh,
                                                       const float* __restrict__ W,
                                                       unsigned short* __restrict__ Zh,
                                                       int n_rows) {
    __shared__ float Wl[64 * 64];        // 16 KB
    __shared__ uint4 Xl4[64 * 8];        // 8 KB: 64 rows x 32 uints (bf16x2)
    int tid = threadIdx.x;
    int lane = tid & 63;
    int wave = tid >> 6;
    int r0 = blockIdx.x * 64;
    int nr = n_rows - r0; if (nr > 64) nr = 64;

    for (int i = tid; i < 64 * 64; i += 256) Wl[i] = W[i];
    const uint4* Xg4 = (const uint4*)(Xh + (size_t)r0 * 32);
    for (int i = tid; i < nr * 8; i += 256) Xl4[i] = Xg4[i];
    __syncthreads();

    const unsigned* Xl = (const unsigned*)Xl4;
    int rbase = wave * 16;
    float acc[16];
#pragma unroll
    for (int i = 0; i < 16; ++i) acc[i] = 0.f;

#pragma unroll 1
    for (int kc = 0; kc < 8; ++kc) {     // 8 k-values per chunk
        float w0 = Wl[(kc * 8 + 0) * 64 + lane];
        float w1 = Wl[(kc * 8 + 1) * 64 + lane];
        float w2 = Wl[(kc * 8 + 2) * 64 + lane];
        float w3 = Wl[(kc * 8 + 3) * 64 + lane];
        float w4 = Wl[(kc * 8 + 4) * 64 + lane];
        float w5 = Wl[(kc * 8 + 5) * 64 + lane];
        float w6 = Wl[(kc * 8 + 6) * 64 + lane];
        float w7 = Wl[(kc * 8 + 7) * 64 + lane];
#pragma unroll
        for (int i = 0; i < 16; ++i) {
            uint4 q = *(const uint4*)&Xl[(rbase + i) * 32 + kc * 4];  // broadcast
            acc[i] = fmaf(bflo(q.x), w0, acc[i]);
            acc[i] = fmaf(bfhi(q.x), w1, acc[i]);
            acc[i] = fmaf(bflo(q.y), w2, acc[i]);
            acc[i] = fmaf(bfhi(q.y), w3, acc[i]);
            acc[i] = fmaf(bflo(q.z), w4, acc[i]);
            acc[i] = fmaf(bfhi(q.z), w5, acc[i]);
            acc[i] = fmaf(bflo(q.w), w6, acc[i]);
            acc[i] = fmaf(bfhi(q.w), w7, acc[i]);
        }
    }
#pragma unroll
    for (int i = 0; i < 16; ++i) {
        int r = r0 + rbase + i;
        if (r < n_rows) Zh[(size_t)r * 64 + lane] = f2bf(acc[i]);
    }
}

// ---------------------------------------------------------------------------
// SPMM + bias + relu (quarter-wave, 16 edges in flight). At the L3-random
// throughput ceiling (~1.7 TB/s fetch): rounds 12/13 two structures gave
// identical 85.6 us / 145 MB FETCH.
// ---------------------------------------------------------------------------
__global__ __launch_bounds__(256) void spmm_bias_relu(const int* __restrict__ row_ptr,
                                                      const int2* __restrict__ packed,
                                                      const uint2* __restrict__ zh2,   // bf16x4, 16/row
                                                      const float* __restrict__ bias,  // [64] fp32
                                                      uint2* __restrict__ outh2,       // bf16x4, 16/row
                                                      int n_rows) {
    int tid = threadIdx.x;
    int lane = tid & 63;
    int wave = tid >> 6;
    int q = lane >> 4;                 // 0..3 quarter
    int k = lane & 15;                 // column group (4 cols per lane)
    int r = blockIdx.x * 4 + wave;
    if (r >= n_rows) return;

    uint2 su = zh2[(size_t)r * 16 + k];
    float4 acc;
    acc.x = q ? 0.f : bflo(su.x);
    acc.y = q ? 0.f : bfhi(su.x);
    acc.z = q ? 0.f : bflo(su.y);
    acc.w = q ? 0.f : bfhi(su.y);

    int e = row_ptr[r] + q;
    int end = row_ptr[r + 1];
    for (; e + 13 < end; e += 16) {    // 16 edges/iter (4 per quarter)
        int2 p0 = packed[e + 0];
        int2 p1 = packed[e + 4];
        int2 p2 = packed[e + 8];
        int2 p3 = packed[e + 12];
        uint2 z0 = zh2[(size_t)p0.x * 16 + k];
        uint2 z1 = zh2[(size_t)p1.x * 16 + k];
        uint2 z2 = zh2[(size_t)p2.x * 16 + k];
        uint2 z3 = zh2[(size_t)p3.x * 16 + k];
        float v0 = __int_as_float(p0.y), v1 = __int_as_float(p1.y);
        float v2 = __int_as_float(p2.y), v3 = __int_as_float(p3.y);
        acc.x = fmaf(v0, bflo(z0.x), acc.x); acc.y = fmaf(v0, bfhi(z0.x), acc.y);
        acc.z = fmaf(v0, bflo(z0.y), acc.z); acc.w = fmaf(v0, bfhi(z0.y), acc.w);
        acc.x = fmaf(v1, bflo(z1.x), acc.x); acc.y = fmaf(v1, bfhi(z1.x), acc.y);
        acc.z = fmaf(v1, bflo(z1.y), acc.z); acc.w = fmaf(v1, bfhi(z1.y), acc.w);
        acc.x = fmaf(v2, bflo(z2.x), acc.x); acc.y = fmaf(v2, bfhi(z2.x), acc.y);
        acc.z = fmaf(v2, bflo(z2.y), acc.z); acc.w = fmaf(v2, bfhi(z2.y), acc.w);
        acc.x = fmaf(v3, bflo(z3.x), acc.x); acc.y = fmaf(v3, bfhi(z3.x), acc.y);
        acc.z = fmaf(v3, bflo(z3.y), acc.z); acc.w = fmaf(v3, bfhi(z3.y), acc.w);
    }
    for (; e < end; e += 4) {
        int2 p = packed[e];
        uint2 z = zh2[(size_t)p.x * 16 + k];
        float v = __int_as_float(p.y);
        acc.x = fmaf(v, bflo(z.x), acc.x); acc.y = fmaf(v, bfhi(z.x), acc.y);
        acc.z = fmaf(v, bflo(z.y), acc.z); acc.w = fmaf(v, bfhi(z.y), acc.w);
    }

    acc.x += __shfl_xor(acc.x, 16, 64);
    acc.y += __shfl_xor(acc.y, 16, 64);
    acc.z += __shfl_xor(acc.z, 16, 64);
    acc.w += __shfl_xor(acc.w, 16, 64);
    acc.x += __shfl_xor(acc.x, 32, 64);
    acc.y += __shfl_xor(acc.y, 32, 64);
    acc.z += __shfl_xor(acc.z, 32, 64);
    acc.w += __shfl_xor(acc.w, 32, 64);
    if (q == 0) {
        float4 bv = ((const float4*)bias)[k];
        float a = fmaxf(acc.x + bv.x, 0.f);
        float b = fmaxf(acc.y + bv.y, 0.f);
        float c = fmaxf(acc.z + bv.z, 0.f);
        float d = fmaxf(acc.w + bv.w, 0.f);
        outh2[(size_t)r * 16 + k] = make_uint2(
            ((unsigned)f2bf(b) << 16) | (unsigned)f2bf(a),
            ((unsigned)f2bf(d) << 16) | (unsigned)f2bf(c));
    }
}

// ---------------------------------------------------------------------------
// Fused MLP: gather_e + gemm384 + mlp23 in one kernel (round-14).
// Per block: 64 batch rows. E-tile built in LDS directly from source tables
// (deletes the 25 MB E round-trip); H-tile relu'd into LDS (deletes the
// 8.4 MB H1 round-trip); W2/W3 finish in-block.
// Segments: [uEmb f32 | feat1h | feat2h | iEmb f32 | feat1h[it+U] | feat2h[it+U]]
// ---------------------------------------------------------------------------
__global__ __launch_bounds__(256) void fused_mlp(
        const int* __restrict__ userIdx, const int* __restrict__ itemIdx,
        const float* __restrict__ uEmb, const float* __restrict__ iEmb,
        const unsigned short* __restrict__ feat1h,
        const unsigned short* __restrict__ feat2h,
        const float* __restrict__ W1, const float* __restrict__ b1,
        const float* __restrict__ W2, const float* __restrict__ b2,
        const float* __restrict__ W3, const float* __restrict__ b3,
        float* __restrict__ out) {
    __shared__ float    Wl[128 * 64];   // 32 KB  W1 chunk
    __shared__ unsigned El[64 * 64];    // 16 KB  E tile (bf16x2)
    __shared__ float    Ht[64 * 64];    // 16 KB  relu(E@W1+b1) tile
    __shared__ float    W2l[64 * 32];   // 8 KB
    __shared__ float    w3l[32];
    __shared__ float    b2l[32];
    __shared__ int      uidx[64], iidx[64];
    int tid = threadIdx.x;
    int lane = tid & 63;
    int wave = tid >> 6;
    int r0 = blockIdx.x * 64;
    int rbase = wave * 16;

    if (tid < 64) uidx[tid] = userIdx[r0 + tid];
    else if (tid < 128) iidx[tid - 64] = itemIdx[r0 + tid - 64];
    if (tid < 32) { w3l[tid] = W3[tid]; b2l[tid] = b2[tid]; }
    for (int i = tid; i < 64 * 32; i += 256) W2l[i] = W2[i];

    float acc[16];
    float bv = b1[lane];
#pragma unroll
    for (int i = 0; i < 16; ++i) acc[i] = bv;

#pragma unroll 1
    for (int c = 0; c < 3; ++c) {
        __syncthreads();   // idx ready (c=0); El/Wl reuse safe (c>0)
        for (int i = tid; i < 128 * 64; i += 256) Wl[i] = W1[c * 128 * 64 + i];
        for (int t = tid; t < 1024; t += 256) {   // 64 rows x 2 segs x 8 quads
            int row = t >> 4;
            int seg = (t >> 3) & 1;
            int q   = t & 7;
            int gseg = c * 2 + seg;               // 0..5
            uint4 val;
            if (gseg == 0 || gseg == 3) {         // fp32 embedding segment
                const float* p = (gseg == 0)
                    ? uEmb + (size_t)uidx[row] * 64 + q * 8
                    : iEmb + (size_t)iidx[row] * 64 + q * 8;
                float4 a = *(const float4*)p;
                float4 b = *(const float4*)(p + 4);
                val.x = ((unsigned)f2bf(a.y) << 16) | f2bf(a.x);
                val.y = ((unsigned)f2bf(a.w) << 16) | f2bf(a.z);
                val.z = ((unsigned)f2bf(b.y) << 16) | f2bf(b.x);
                val.w = ((unsigned)f2bf(b.w) << 16) | f2bf(b.z);
            } else {
                const unsigned short* src;
                if (gseg == 1)      src = feat1h + (size_t)uidx[row] * 64;
                else if (gseg == 2) src = feat2h + (size_t)uidx[row] * 64;
                else if (gseg == 4) src = feat1h + (size_t)(iidx[row] + NUM_USERS) * 64;
                else                src = feat2h + (size_t)(iidx[row] + NUM_USERS) * 64;
                val = *(const uint4*)(src + q * 8);
            }
            *(uint4*)&El[row * 64 + seg * 32 + q * 4] = val;
        }
        __syncthreads();
        const uint4* El4 = (const uint4*)El;
#pragma unroll 1
        for (int k = 0; k < 128; k += 8) {
            float w0 = Wl[(k + 0) * 64 + lane];
            float w1 = Wl[(k + 1) * 64 + lane];
            float w2 = Wl[(k + 2) * 64 + lane];
            float w3 = Wl[(k + 3) * 64 + lane];
            float w4 = Wl[(k + 4) * 64 + lane];
            float w5 = Wl[(k + 5) * 64 + lane];
            float w6 = Wl[(k + 6) * 64 + lane];
            float w7 = Wl[(k + 7) * 64 + lane];
#pragma unroll
            for (int i = 0; i < 16; ++i) {
                uint4 q = El4[(rbase + i) * 16 + (k >> 3)];   // LDS broadcast
                acc[i] = fmaf(bflo(q.x), w0, acc[i]);
                acc[i] = fmaf(bfhi(q.x), w1, acc[i]);
                acc[i] = fmaf(bflo(q.y), w2, acc[i]);
                acc[i] = fmaf(bfhi(q.y), w3, acc[i]);
                acc[i] = fmaf(bflo(q.z), w4, acc[i]);
                acc[i] = fmaf(bfhi(q.z), w5, acc[i]);
                acc[i] = fmaf(bflo(q.w), w6, acc[i]);
                acc[i] = fmaf(bfhi(q.w), w7, acc[i]);
            }
        }
    }

    // H-tile: relu
#pragma unroll
    for (int i = 0; i < 16; ++i) Ht[(rbase + i) * 64 + lane] = fmaxf(acc[i], 0.f);
    __syncthreads();

    // W2/W3 finish: half-wave per row (lanes k<32 = W2 cols), shfl reduce
    int half = lane >> 5;
    int k = lane & 31;
    float b3v = b3[0];
#pragma unroll 1
    for (int p = 0; p < 8; ++p) {
        int row = rbase + p * 2 + half;
        float z = b2l[k];
#pragma unroll
        for (int j = 0; j < 64; ++j)
            z = fmaf(Ht[row * 64 + j], W2l[j * 32 + k], z);
        z *= w3l[k];
#pragma unroll
        for (int off = 16; off; off >>= 1)
            z += __shfl_xor(z, off, 64);
        if (k == 0) out[r0 + row] = z + b3v;
    }
}

// ---------------------------------------------------------------------------
extern "C" void kernel_launch(void* const* d_in, const int* in_sizes, int n_in,
                              void* d_out, int out_size, void* d_ws, size_t ws_size,
                              hipStream_t stream) {
    const int*   userIdx = (const int*)  d_in[0];
    const int*   itemIdx = (const int*)  d_in[1];
    const int*   lap_rows= (const int*)  d_in[2];
    const int*   lap_cols= (const int*)  d_in[3];
    const float* lap_vals= (const float*)d_in[4];
    const float* uEmb    = (const float*)d_in[5];
    const float* iEmb    = (const float*)d_in[6];
    const float* gW0     = (const float*)d_in[7];
    const float* gb0     = (const float*)d_in[8];
    const float* gW1     = (const float*)d_in[9];
    const float* gb1     = (const float*)d_in[10];
    const float* W1      = (const float*)d_in[11];
    const float* b1      = (const float*)d_in[12];
    const float* W2      = (const float*)d_in[13];
    const float* b2      = (const float*)d_in[14];
    const float* W3      = (const float*)d_in[15];
    const float* b3      = (const float*)d_in[16];
    float* out = (float*)d_out;

    const size_t NF = (size_t)N_NODES * EMB;              // 9.6M elements
    char* w = (char*)d_ws;
    unsigned short* bufA = (unsigned short*)w;            // feat1h (19.2 MB)
    unsigned short* bufB = bufA + NF;                     // feat2h (19.2 MB)
    char*  region3 = (char*)(bufB + NF);                  // 38.4 MB multi-use
    // region3 first half: pv during CSR build, then Zh
    int2*  pv      = (int2*)region3;                      // 19.2 MB (dead after fine_scatter)
    unsigned short* Zh = (unsigned short*)region3;        // Z table (19.2 MB)
    // region3 second half: packed lives through both spmm calls
    int2*  packed  = (int2*)(region3 + NF * sizeof(float)); // 19.2 MB
    int*   row_ptr = (int*)(packed + NNZ);                // N_NODES+1
    int*   boffs   = row_ptr + (N_NODES + 1);             // NBUCK+1 (immutable)
    int*   gtails  = boffs + (NBUCK + 1);                 // NBUCK (mutable tails)
    int*   bcnt    = gtails + NBUCK;                      // NBUCK

    const int ms_grid   = (NNZ + EPB - 1) / EPB;          // 293
    const int spmm_grid = (N_NODES + 3) / 4;              // 37500
    const int gemm_grid = (N_NODES + 63) / 64;            // 2344

    // ---- Build bucketed CSR (shared by both layers)
    hipMemsetAsync(bcnt, 0, NBUCK * sizeof(int), stream);
    bucket_hist<<<128, 1024, 0, stream>>>(lap_rows, bcnt, NNZ);
    bucket_scan<<<1, 1024, 0, stream>>>(bcnt, boffs, gtails, NNZ);
    coarse_multisplit<<<ms_grid, 1024, 0, stream>>>(lap_rows, lap_cols, lap_vals,
                                                    gtails, pv, NNZ);
    fine_scatter<<<NBUCK, 1024, 0, stream>>>(boffs, pv, packed, row_ptr, NNZ);

    // ---- Layer 1: Z = concat(uEmb,iEmb)@gW0 ; feat1 = relu((L+I)Z + gb0)
    gemm_table_f32<<<gemm_grid, 256, 0, stream>>>(uEmb, iEmb, gW0, Zh, N_NODES);
    spmm_bias_relu<<<spmm_grid, 256, 0, stream>>>(row_ptr, packed, (const uint2*)Zh,
                                                  gb0, (uint2*)bufA, N_NODES);

    // ---- Layer 2: Z = feat1@gW1 ; feat2 = relu((L+I)Z + gb1)
    gemm_table_bf16<<<gemm_grid, 256, 0, stream>>>((const unsigned*)bufA, gW1, Zh, N_NODES);
    spmm_bias_relu<<<spmm_grid, 256, 0, stream>>>(row_ptr, packed, (const uint2*)Zh,
                                                  gb1, (uint2*)bufB, N_NODES);

    // ---- Fused MLP: gather + E@W1+b1+relu + @W2+b2 + @W3+b3
    fused_mlp<<<BATCH / 64, 256, 0, stream>>>(userIdx, itemIdx, uEmb, iEmb,
                                              bufA, bufB, W1, b1, W2, b2, W3, b3, out);
}